// Round 10
// baseline (418.891 us; speedup 1.0000x reference)
//
#include <hip/hip_runtime.h>
#include <math.h>

#define H1 100
#define H3 300

// bf16 W^T regions in d_ws (short-element offsets from byte 64)
#define WT_TM1    0
#define WT_TM2    14336
#define WT_VS     28672
#define WT_VV     43008        // 304x320
#define NSHORT    140288
// fp32 padded small-weight region (float-element offsets after bf16 region)
#define F_TM1W1   0
#define F_TM1B1   256
#define F_TM2W1   384
#define F_TM2B1   640
#define F_VSW1    768
#define F_VSB1    1024
#define F_VVW1    1152
#define F_VVB1    1792
#define F_TM1B2   2112
#define F_TM2B2   2240
#define F_VSB2    2368
#define F_VVB2    2496
#define F_TM1W3T  2816         // [2][128]
#define F_TM2W3T  3072         // [2][128]
#define F_VSW3T   3328         // [1][128]
#define F_VVW3T   3456         // [2][320]
#define NFLOAT    4096

typedef __attribute__((ext_vector_type(8))) short s8v;
typedef __attribute__((ext_vector_type(4))) float f4v;

__device__ __forceinline__ f4v mfma16(s8v a, s8v b, f4v c) {
    return __builtin_amdgcn_mfma_f32_16x16x32_bf16(a, b, c, 0, 0, 0);
}
__device__ __forceinline__ float rcp_fast(float v) { return __builtin_amdgcn_rcpf(v); }
__device__ __forceinline__ float tanh_fast(float v) {
    float t = __expf(2.f * v);
    return 1.f - 2.f * rcp_fast(t + 1.f);
}
__device__ __forceinline__ float leakyf(float v) { return v >= 0.f ? v : 0.01f * v; }
__device__ __forceinline__ float preluf(float v, float a) { return v >= 0.f ? v : a * v; }
__device__ __forceinline__ short f2bf(float f) {
    union { float f; unsigned u; } v; v.f = f;
    unsigned r = v.u + 0x7fffu + ((v.u >> 16) & 1u);   // RNE
    return (short)(r >> 16);
}
// reduce across the 4 fq lane-groups (lane bits 4,5); result in every lane
#define RED4(v) { v += __shfl_xor(v, 16, 64); v += __shfl_xor(v, 32, 64); }

__device__ __forceinline__ void loadB4(s8v* dst, const short* p) {
    dst[0] = *(const s8v*)(p);
    dst[1] = *(const s8v*)(p + 32);
    dst[2] = *(const s8v*)(p + 64);
    dst[3] = *(const s8v*)(p + 96);
}
__device__ __forceinline__ void loadH5(s8v* dst, const short* p) {
    dst[0] = *(const s8v*)(p);
    dst[1] = *(const s8v*)(p + 32);
    dst[2] = *(const s8v*)(p + 64);
    dst[3] = *(const s8v*)(p + 96);
    dst[4] = *(const s8v*)(p + 128);
}

// ---------------------------------------------------------------------------
// prep: bf16 W^T regions + fp32 padded L1 weights / biases / transposed W3 + origin
// ---------------------------------------------------------------------------
__global__ void ngdv_prep(
    const float* __restrict__ tm1_w1, const float* __restrict__ tm1_b1,
    const float* __restrict__ tm1_w2, const float* __restrict__ tm1_b2,
    const float* __restrict__ tm1_w3, const float* __restrict__ tm1_b3,
    const float* __restrict__ tm2_w1, const float* __restrict__ tm2_b1,
    const float* __restrict__ tm2_w2, const float* __restrict__ tm2_b2,
    const float* __restrict__ tm2_w3, const float* __restrict__ tm2_b3,
    const float* __restrict__ vs_w1,  const float* __restrict__ vs_b1,
    const float* __restrict__ vs_w2,  const float* __restrict__ vs_b2,
    const float* __restrict__ vs_w3,
    const float* __restrict__ vv_w1,  const float* __restrict__ vv_b1,
    const float* __restrict__ vv_w2,  const float* __restrict__ vv_b2,
    const float* __restrict__ vv_w3,
    short* __restrict__ wsb, float* __restrict__ wsf, float* __restrict__ origin_out)
{
    const int tid = threadIdx.x;
    if (blockIdx.x < 564) {
        int idx = blockIdx.x * 256 + tid;
        if (idx < NSHORT) {
            short o;
            if (idx < WT_TM2)      { int n = idx >> 7, k = idx & 127; o = (n < H1 && k < H1) ? f2bf(tm1_w2[k*H1 + n]) : (short)0; }
            else if (idx < WT_VS)  { int r = idx - WT_TM2, n = r >> 7, k = r & 127; o = (n < H1 && k < H1) ? f2bf(tm2_w2[k*H1 + n]) : (short)0; }
            else if (idx < WT_VV)  { int r = idx - WT_VS,  n = r >> 7, k = r & 127; o = (n < H1 && k < H1) ? f2bf(vs_w2[k*H1 + n]) : (short)0; }
            else                   { int r = idx - WT_VV,  n = r / 320, k = r % 320; o = (n < H3 && k < H3) ? f2bf(vv_w2[k*H3 + n]) : (short)0; }
            wsb[idx] = o;
        } else {
            int f = idx - NSHORT;
            if (f < NFLOAT) {
                float v = 0.f;
                if (f < 256)       { int d = f >> 7, c = f & 127; if (c < H1) v = tm1_w1[d*H1 + c]; }
                else if (f < 384)  { int c = f - 256;  if (c < H1) v = tm1_b1[c]; }
                else if (f < 640)  { int r = f - 384, d = r >> 7, c = r & 127; if (c < H1) v = tm2_w1[d*H1 + c]; }
                else if (f < 768)  { int c = f - 640;  if (c < H1) v = tm2_b1[c]; }
                else if (f < 1024) { int r = f - 768, d = r >> 7, c = r & 127; if (c < H1) v = vs_w1[d*H1 + c]; }
                else if (f < 1152) { int c = f - 1024; if (c < H1) v = vs_b1[c]; }
                else if (f < 1792) { int r = f - 1152, d = r / 320, c = r % 320; if (c < H3) v = vv_w1[d*H3 + c]; }
                else if (f < 2112) { int c = f - 1792; if (c < H3) v = vv_b1[c]; }
                else if (f < 2240) { int c = f - 2112; if (c < H1) v = tm1_b2[c]; }
                else if (f < 2368) { int c = f - 2240; if (c < H1) v = tm2_b2[c]; }
                else if (f < 2496) { int c = f - 2368; if (c < H1) v = vs_b2[c]; }
                else if (f < 2816) { int c = f - 2496; if (c < H3) v = vv_b2[c]; }
                else if (f < 3072) { int r = f - 2816, i = r >> 7, c = r & 127; if (c < H1) v = tm1_w3[c*2 + i]; }
                else if (f < 3328) { int r = f - 3072, i = r >> 7, c = r & 127; if (c < H1) v = tm2_w3[c*2 + i]; }
                else if (f < 3456) { int c = f - 3328; if (c < H1) v = vs_w3[c]; }
                else               { int r = f - 3456, i = r / 320, c = r % 320; if (c < H3) v = vv_w3[c*2 + i]; }
                wsf[f] = v;
            }
        }
        return;
    }
    // origin block: taskmap(0). 256 threads: r = output idx, hf = k-half, shfl combine.
    __shared__ float h1[H1], h2[H1], y1o[2], g1[H1], g2[H1];
    const int r = tid >> 1, hf = tid & 1;
    const int k0 = hf ? 50 : 0, k1 = hf ? 100 : 50;
    if (tid < H1) h1[tid] = tanhf(tm1_b1[tid]);
    __syncthreads();
    {
        float acc = 0.f;
        if (r < H1) for (int k = k0; k < k1; ++k) acc += h1[k] * tm1_w2[k*H1 + r];
        acc += __shfl_xor(acc, 1, 64);
        if (r < H1 && !hf) h2[r] = tanhf(acc + tm1_b2[r]);
    }
    __syncthreads();
    if (tid < 2) {
        float acc = tm1_b3[tid];
        for (int k = 0; k < H1; ++k) acc += h2[k] * tm1_w3[k*2 + tid];
        y1o[tid] = acc;
    }
    __syncthreads();
    if (tid < H1) {
        float pre = tm2_b1[tid] + y1o[0]*tm2_w1[tid] + y1o[1]*tm2_w1[H1 + tid];
        g1[tid] = pre > 0.f ? pre : expm1f(pre);
    }
    __syncthreads();
    {
        float acc = 0.f;
        if (r < H1) for (int k = k0; k < k1; ++k) acc += g1[k] * tm2_w2[k*H1 + r];
        acc += __shfl_xor(acc, 1, 64);
        if (r < H1 && !hf) { float a = acc + tm2_b2[r]; g2[r] = a > 0.f ? a : expm1f(a); }
    }
    __syncthreads();
    if (tid < 2) {
        float acc = tm2_b3[tid];
        for (int k = 0; k < H1; ++k) acc += g2[k] * tm2_w3[k*2 + tid];
        float s = acc > 20.f ? acc : log1pf(expf(acc));
        origin_out[tid] = (1.f + s) * y1o[tid];
    }
}

// ---------------------------------------------------------------------------
// Main: ZERO LDS, register dataflow, 16 points/wave. L3 reductions folded into
// GEMM epilogues + shfl_xor. R10: vectorized L1 weight loads (f4v) + B-fragment
// software pipelining (double/triple buffers) to cover L2 latency with ILP.
// ---------------------------------------------------------------------------
__global__ __launch_bounds__(256, 2) void ngdv_main(
    const float* __restrict__ x,
    const float* __restrict__ tm1_b3, const float* __restrict__ tm2_b3,
    const float* __restrict__ vs_b3,  const float* __restrict__ vv_b3,
    const float* __restrict__ vv_a1,  const float* __restrict__ vv_a2,
    const short* __restrict__ wsb,    const float* __restrict__ wsf,
    const float* __restrict__ origin, float* __restrict__ out, int npts)
{
    const int tid = threadIdx.x;
    const int wv = tid >> 6, lane = tid & 63;
    const int fm = lane & 15, fq = lane >> 4;
    const int p = blockIdx.x*64 + wv*16 + fm;
    float2 xv = {0.f, 0.f};
    if (p < npts) xv = *(const float2*)&x[p*2];
    const float a1v = vv_a1[0], a2v = vv_a2[0];
    const float og0 = origin[0], og1 = origin[1];

    s8v afp[4], aft0[4], aft1[4];
    s8v Ba[4], Bb[4];

    // ---- tm1 L1 (2->100) + tangent seeds (vectorized weight loads)
    #pragma unroll
    for (int ks = 0; ks < 4; ++ks) {
        int c0 = ks*32 + fq*8;
        s8v hv, t0v, t1v;
        #pragma unroll
        for (int hh = 0; hh < 2; ++hh) {
            f4v w0 = *(const f4v*)&wsf[F_TM1W1 + c0 + hh*4];
            f4v w1 = *(const f4v*)&wsf[F_TM1W1 + 128 + c0 + hh*4];
            f4v bv = *(const f4v*)&wsf[F_TM1B1 + c0 + hh*4];
            #pragma unroll
            for (int e = 0; e < 4; ++e) {
                int ee = hh*4 + e;
                float pre = fmaf(xv.y, w1[e], fmaf(xv.x, w0[e], bv[e]));
                float h = tanh_fast(pre), dd = 1.f - h*h;
                hv[ee] = f2bf(h); t0v[ee] = f2bf(w0[e]*dd); t1v[ee] = f2bf(w1[e]*dd);
            }
        }
        afp[ks] = hv; aft0[ks] = t0v; aft1[ks] = t1v;
    }

    // ---- G1: [48x128]@tm1_w2; B double-buffered; epilogue folds tanh + L3
    float y1p0 = 0.f, y1p1 = 0.f, dyp00 = 0.f, dyp01 = 0.f, dyp10 = 0.f, dyp11 = 0.f;
    {
        const short* bb = wsb + WT_TM1 + fm*128 + fq*8;
        loadB4(Ba, bb);
        #pragma unroll
        for (int nt = 0; nt < 7; ++nt) {
            s8v* cur = (nt & 1) ? Bb : Ba;
            s8v* nxt = (nt & 1) ? Ba : Bb;
            if (nt < 6) loadB4(nxt, bb + (nt+1)*2048);
            f4v cp = {0,0,0,0}, ct0 = {0,0,0,0}, ct1 = {0,0,0,0};
            cp  = mfma16(cur[0], afp[0], cp);   cp  = mfma16(cur[1], afp[1], cp);
            cp  = mfma16(cur[2], afp[2], cp);   cp  = mfma16(cur[3], afp[3], cp);
            ct0 = mfma16(cur[0], aft0[0], ct0); ct0 = mfma16(cur[1], aft0[1], ct0);
            ct0 = mfma16(cur[2], aft0[2], ct0); ct0 = mfma16(cur[3], aft0[3], ct0);
            ct1 = mfma16(cur[0], aft1[0], ct1); ct1 = mfma16(cur[1], aft1[1], ct1);
            ct1 = mfma16(cur[2], aft1[2], ct1); ct1 = mfma16(cur[3], aft1[3], ct1);
            int col0 = nt*16 + fq*4;
            f4v bb2 = *(const f4v*)&wsf[F_TM1B2 + col0];
            f4v w0v = *(const f4v*)&wsf[F_TM1W3T + col0];
            f4v w1v = *(const f4v*)&wsf[F_TM1W3T + 128 + col0];
            #pragma unroll
            for (int r = 0; r < 4; ++r) {
                float h = tanh_fast(cp[r] + bb2[r]);
                float dd = 1.f - h*h;
                float t0 = ct0[r]*dd, t1 = ct1[r]*dd;
                y1p0  = fmaf(h,  w0v[r], y1p0);  y1p1  = fmaf(h,  w1v[r], y1p1);
                dyp00 = fmaf(t0, w0v[r], dyp00); dyp01 = fmaf(t0, w1v[r], dyp01);
                dyp10 = fmaf(t1, w0v[r], dyp10); dyp11 = fmaf(t1, w1v[r], dyp11);
            }
        }
    }
    RED4(y1p0); RED4(y1p1); RED4(dyp00); RED4(dyp01); RED4(dyp10); RED4(dyp11);
    const float y10 = y1p0 + tm1_b3[0] + xv.x;
    const float y11 = y1p1 + tm1_b3[1] + xv.y;
    const float dy00 = dyp00 + 1.f, dy01 = dyp01;
    const float dy10 = dyp10, dy11 = dyp11 + 1.f;

    // ---- tm2 L1 (2->100) + tangent seeds
    #pragma unroll
    for (int ks = 0; ks < 4; ++ks) {
        int c0 = ks*32 + fq*8;
        s8v hv, t0v, t1v;
        #pragma unroll
        for (int hh = 0; hh < 2; ++hh) {
            f4v w0 = *(const f4v*)&wsf[F_TM2W1 + c0 + hh*4];
            f4v w1 = *(const f4v*)&wsf[F_TM2W1 + 128 + c0 + hh*4];
            f4v bv = *(const f4v*)&wsf[F_TM2B1 + c0 + hh*4];
            #pragma unroll
            for (int e = 0; e < 4; ++e) {
                int ee = hh*4 + e;
                float pre = fmaf(y11, w1[e], fmaf(y10, w0[e], bv[e]));
                float g = pre > 0.f ? pre : (__expf(pre) - 1.f);
                float dd = pre > 0.f ? 1.f : (g + 1.f);
                hv[ee] = f2bf(g);
                t0v[ee] = f2bf((dy00*w0[e] + dy01*w1[e]) * dd);
                t1v[ee] = f2bf((dy10*w0[e] + dy11*w1[e]) * dd);
            }
        }
        afp[ks] = hv; aft0[ks] = t0v; aft1[ks] = t1v;
    }

    // ---- G2: [48x128]@tm2_w2; B double-buffered; epilogue folds elu + L3
    float spp0 = 0.f, spp1 = 0.f, dsp00 = 0.f, dsp01 = 0.f, dsp10 = 0.f, dsp11 = 0.f;
    {
        const short* bb = wsb + WT_TM2 + fm*128 + fq*8;
        loadB4(Ba, bb);
        #pragma unroll
        for (int nt = 0; nt < 7; ++nt) {
            s8v* cur = (nt & 1) ? Bb : Ba;
            s8v* nxt = (nt & 1) ? Ba : Bb;
            if (nt < 6) loadB4(nxt, bb + (nt+1)*2048);
            f4v cp = {0,0,0,0}, ct0 = {0,0,0,0}, ct1 = {0,0,0,0};
            cp  = mfma16(cur[0], afp[0], cp);   cp  = mfma16(cur[1], afp[1], cp);
            cp  = mfma16(cur[2], afp[2], cp);   cp  = mfma16(cur[3], afp[3], cp);
            ct0 = mfma16(cur[0], aft0[0], ct0); ct0 = mfma16(cur[1], aft0[1], ct0);
            ct0 = mfma16(cur[2], aft0[2], ct0); ct0 = mfma16(cur[3], aft0[3], ct0);
            ct1 = mfma16(cur[0], aft1[0], ct1); ct1 = mfma16(cur[1], aft1[1], ct1);
            ct1 = mfma16(cur[2], aft1[2], ct1); ct1 = mfma16(cur[3], aft1[3], ct1);
            int col0 = nt*16 + fq*4;
            f4v bb2 = *(const f4v*)&wsf[F_TM2B2 + col0];
            f4v w0v = *(const f4v*)&wsf[F_TM2W3T + col0];
            f4v w1v = *(const f4v*)&wsf[F_TM2W3T + 128 + col0];
            #pragma unroll
            for (int r = 0; r < 4; ++r) {
                float pre = cp[r] + bb2[r];
                float g = pre > 0.f ? pre : (__expf(pre) - 1.f);
                float dd = pre > 0.f ? 1.f : (g + 1.f);
                float t0 = ct0[r]*dd, t1 = ct1[r]*dd;
                spp0  = fmaf(g,  w0v[r], spp0);  spp1  = fmaf(g,  w1v[r], spp1);
                dsp00 = fmaf(t0, w0v[r], dsp00); dsp01 = fmaf(t0, w1v[r], dsp01);
                dsp10 = fmaf(t1, w0v[r], dsp10); dsp11 = fmaf(t1, w1v[r], dsp11);
            }
        }
    }
    RED4(spp0); RED4(spp1); RED4(dsp00); RED4(dsp01); RED4(dsp10); RED4(dsp11);
    float ys0, ys1, Ja, Jb, Jc, Jd;
    {
        float sp0 = spp0 + tm2_b3[0], sp1 = spp1 + tm2_b3[1];
        float s0 = sp0 > 20.f ? sp0 : __logf(1.f + __expf(sp0));
        float s1 = sp1 > 20.f ? sp1 : __logf(1.f + __expf(sp1));
        float sg0 = rcp_fast(1.f + __expf(-sp0));
        float sg1 = rcp_fast(1.f + __expf(-sp1));
        Ja = dsp00*sg0*y10 + (1.f + s0)*dy00;   // i=0,d=0
        Jb = dsp10*sg0*y10 + (1.f + s0)*dy10;   // i=0,d=1
        Jc = dsp01*sg1*y11 + (1.f + s1)*dy01;   // i=1,d=0
        Jd = dsp11*sg1*y11 + (1.f + s1)*dy11;   // i=1,d=1
        ys0 = (1.f + s0)*y10 - og0;
        ys1 = (1.f + s1)*y11 - og1;
    }

    // ---- vs L1 (2->100)
    #pragma unroll
    for (int ks = 0; ks < 4; ++ks) {
        int c0 = ks*32 + fq*8;
        s8v hv;
        #pragma unroll
        for (int hh = 0; hh < 2; ++hh) {
            f4v w0 = *(const f4v*)&wsf[F_VSW1 + c0 + hh*4];
            f4v w1 = *(const f4v*)&wsf[F_VSW1 + 128 + c0 + hh*4];
            f4v bv = *(const f4v*)&wsf[F_VSB1 + c0 + hh*4];
            #pragma unroll
            for (int e = 0; e < 4; ++e)
                hv[hh*4+e] = f2bf(leakyf(fmaf(xv.y, w1[e], fmaf(xv.x, w0[e], bv[e]))));
        }
        afp[ks] = hv;
    }

    // ---- G3: [16x128]@vs_w2; B double-buffered; epilogue folds leaky + L3
    float lvp = 0.f;
    {
        const short* bb = wsb + WT_VS + fm*128 + fq*8;
        loadB4(Ba, bb);
        #pragma unroll
        for (int nt = 0; nt < 7; ++nt) {
            s8v* cur = (nt & 1) ? Bb : Ba;
            s8v* nxt = (nt & 1) ? Ba : Bb;
            if (nt < 6) loadB4(nxt, bb + (nt+1)*2048);
            f4v cp = {0,0,0,0};
            cp = mfma16(cur[0], afp[0], cp); cp = mfma16(cur[1], afp[1], cp);
            cp = mfma16(cur[2], afp[2], cp); cp = mfma16(cur[3], afp[3], cp);
            int col0 = nt*16 + fq*4;
            f4v bb2 = *(const f4v*)&wsf[F_VSB2 + col0];
            f4v w0v = *(const f4v*)&wsf[F_VSW3T + col0];
            #pragma unroll
            for (int r = 0; r < 4; ++r)
                lvp = fmaf(leakyf(cp[r] + bb2[r]), w0v[r], lvp);
        }
    }
    RED4(lvp);
    const float lv = lvp + vs_b3[0];

    // ---- vv L1 (2->300) -> 10 register A-frags
    s8v afw[10];
    #pragma unroll
    for (int ks = 0; ks < 10; ++ks) {
        int c0 = ks*32 + fq*8;
        s8v hv;
        #pragma unroll
        for (int hh = 0; hh < 2; ++hh) {
            f4v w0 = *(const f4v*)&wsf[F_VVW1 + c0 + hh*4];
            f4v w1 = *(const f4v*)&wsf[F_VVW1 + 320 + c0 + hh*4];
            f4v bv = *(const f4v*)&wsf[F_VVB1 + c0 + hh*4];
            #pragma unroll
            for (int e = 0; e < 4; ++e)
                hv[hh*4+e] = f2bf(preluf(fmaf(ys1, w1[e], fmaf(ys0, w0[e], bv[e])), a1v));
        }
        afw[ks] = hv;
    }

    // ---- G4: [16x320]@vv_w2; 3-buffer half-tile pipeline; epilogue folds prelu + L3
    float dtp0 = 0.f, dtp1 = 0.f;
    {
        const short* bb = wsb + WT_VV + fm*320 + fq*8;
        s8v H[3][5];
        loadH5(H[0], bb);            // tile0 half0
        loadH5(H[1], bb + 160);      // tile0 half1
        #pragma unroll
        for (int nt = 0; nt < 19; ++nt) {
            const int i0 = (2*nt) % 3, i1 = (2*nt + 1) % 3, i2 = (2*nt + 2) % 3;
            if (nt < 18) loadH5(H[i2], bb + (nt+1)*5120);          // next tile half0
            f4v ca = {0,0,0,0}, cb = {0,0,0,0};
            ca = mfma16(H[i0][0], afw[0], ca); cb = mfma16(H[i0][1], afw[1], cb);
            ca = mfma16(H[i0][2], afw[2], ca); cb = mfma16(H[i0][3], afw[3], cb);
            ca = mfma16(H[i0][4], afw[4], ca);
            if (nt < 18) loadH5(H[i0], bb + (nt+1)*5120 + 160);    // next tile half1 (reuses i0)
            cb = mfma16(H[i1][0], afw[5], cb); ca = mfma16(H[i1][1], afw[6], ca);
            cb = mfma16(H[i1][2], afw[7], cb); ca = mfma16(H[i1][3], afw[8], ca);
            cb = mfma16(H[i1][4], afw[9], cb);
            f4v cp = ca + cb;
            int col0 = nt*16 + fq*4;
            f4v bb2 = *(const f4v*)&wsf[F_VVB2 + col0];
            f4v w0v = *(const f4v*)&wsf[F_VVW3T + col0];
            f4v w1v = *(const f4v*)&wsf[F_VVW3T + 320 + col0];
            #pragma unroll
            for (int r = 0; r < 4; ++r) {
                float v = preluf(cp[r] + bb2[r], a2v);
                dtp0 = fmaf(v, w0v[r], dtp0);
                dtp1 = fmaf(v, w1v[r], dtp1);
            }
        }
    }
    RED4(dtp0); RED4(dtp1);
    const float dt0 = dtp0 + vv_b3[0];
    const float dt1 = dtp1 + vv_b3[1];

    // ---- combine & store (all lanes hold everything; fq==0 stores)
    if (fq == 0 && p < npts) {
        float ls = dt0*ys0 + dt1*ys1;
        float Vq = ys0*ys0 + ys1*ys1;
        float coef = fmaxf(ls + 1e-4f*Vq, 0.f) * rcp_fast(Vq + 1e-12f);
        float yd0 = dt0 - coef*ys0, yd1 = dt1 - coef*ys1;
        float inv_n = rcp_fast(fmaxf(sqrtf(yd0*yd0 + yd1*yd1), 1e-12f));
        float yn0 = yd0*inv_n, yn1 = yd1*inv_n;
        float invdet = rcp_fast(Ja*Jd - Jb*Jc);
        float xh0 = ( Jd*yn0 - Jb*yn1) * invdet;
        float xh1 = (-Jc*yn0 + Ja*yn1) * invdet;
        float2 o;
        o.x = (__expf(lv + xv.x) + 1e-12f) * xh0;
        o.y = (__expf(lv + xv.y) + 1e-12f) * xh1;
        *(float2*)&out[p*2] = o;
    }
}

extern "C" void kernel_launch(void* const* d_in, const int* in_sizes, int n_in,
                              void* d_out, int out_size, void* d_ws, size_t ws_size,
                              hipStream_t stream) {
    const float* x      = (const float*)d_in[0];
    const float* tm1_w1 = (const float*)d_in[1];
    const float* tm1_b1 = (const float*)d_in[2];
    const float* tm1_w2 = (const float*)d_in[3];
    const float* tm1_b2 = (const float*)d_in[4];
    const float* tm1_w3 = (const float*)d_in[5];
    const float* tm1_b3 = (const float*)d_in[6];
    const float* tm2_w1 = (const float*)d_in[7];
    const float* tm2_b1 = (const float*)d_in[8];
    const float* tm2_w2 = (const float*)d_in[9];
    const float* tm2_b2 = (const float*)d_in[10];
    const float* tm2_w3 = (const float*)d_in[11];
    const float* tm2_b3 = (const float*)d_in[12];
    const float* vv_w1  = (const float*)d_in[13];
    const float* vv_b1  = (const float*)d_in[14];
    const float* vv_a1  = (const float*)d_in[15];
    const float* vv_w2  = (const float*)d_in[16];
    const float* vv_b2  = (const float*)d_in[17];
    const float* vv_a2  = (const float*)d_in[18];
    const float* vv_w3  = (const float*)d_in[19];
    const float* vv_b3  = (const float*)d_in[20];
    const float* vs_w1  = (const float*)d_in[21];
    const float* vs_b1  = (const float*)d_in[22];
    const float* vs_w2  = (const float*)d_in[23];
    const float* vs_b2  = (const float*)d_in[24];
    const float* vs_w3  = (const float*)d_in[25];
    const float* vs_b3  = (const float*)d_in[26];

    float* out       = (float*)d_out;
    float* origin_ws = (float*)d_ws;                            // 2 floats
    short* wsb       = (short*)((char*)d_ws + 64);              // bf16 regions
    float* wsf       = (float*)((char*)d_ws + 64 + NSHORT*2);   // fp32 padded region
    const int npts = in_sizes[0] / 2;
    const int nblk = (npts + 63) / 64;

    ngdv_prep<<<565, 256, 0, stream>>>(
        tm1_w1, tm1_b1, tm1_w2, tm1_b2, tm1_w3, tm1_b3,
        tm2_w1, tm2_b1, tm2_w2, tm2_b2, tm2_w3, tm2_b3,
        vs_w1, vs_b1, vs_w2, vs_b2, vs_w3,
        vv_w1, vv_b1, vv_w2, vv_b2, vv_w3,
        wsb, wsf, origin_ws);

    ngdv_main<<<nblk, 256, 0, stream>>>(
        x, tm1_b3, tm2_b3, vs_b3, vv_b3, vv_a1, vv_a2,
        wsb, wsf, origin_ws, out, npts);
}

// Round 11
// 405.862 us; speedup vs baseline: 1.0321x; 1.0321x over previous
//
#include <hip/hip_runtime.h>
#include <math.h>

#define H1 100
#define H3 300

// bf16 W^T regions in d_ws (short-element offsets from byte 64)
#define WT_TM1    0
#define WT_TM2    14336
#define WT_VS     28672
#define WT_VV     43008        // 304x320
#define NSHORT    140288
// fp32 padded small-weight region (float-element offsets after bf16 region)
#define F_TM1W1   0
#define F_TM1B1   256
#define F_TM2W1   384
#define F_TM2B1   640
#define F_VSW1    768
#define F_VSB1    1024
#define F_VVW1    1152
#define F_VVB1    1792
#define F_TM1B2   2112
#define F_TM2B2   2240
#define F_VSB2    2368
#define F_VVB2    2496
#define F_TM1W3T  2816         // [2][128]
#define F_TM2W3T  3072         // [2][128]
#define F_VSW3T   3328         // [1][128]
#define F_VVW3T   3456         // [2][320]
#define NFLOAT    4096

typedef __attribute__((ext_vector_type(8))) short s8v;
typedef __attribute__((ext_vector_type(4))) float f4v;

__device__ __forceinline__ f4v mfma16(s8v a, s8v b, f4v c) {
    return __builtin_amdgcn_mfma_f32_16x16x32_bf16(a, b, c, 0, 0, 0);
}
__device__ __forceinline__ float rcp_fast(float v) { return __builtin_amdgcn_rcpf(v); }
__device__ __forceinline__ float tanh_fast(float v) {
    float t = __expf(2.f * v);
    return 1.f - 2.f * rcp_fast(t + 1.f);
}
__device__ __forceinline__ float leakyf(float v) { return v >= 0.f ? v : 0.01f * v; }
__device__ __forceinline__ float preluf(float v, float a) { return v >= 0.f ? v : a * v; }
__device__ __forceinline__ short f2bf(float f) {
    union { float f; unsigned u; } v; v.f = f;
    unsigned r = v.u + 0x7fffu + ((v.u >> 16) & 1u);   // RNE
    return (short)(r >> 16);
}
// reduce across the 4 fq lane-groups (lane bits 4,5); result in every lane
#define RED4(v) { v += __shfl_xor(v, 16, 64); v += __shfl_xor(v, 32, 64); }

__device__ __forceinline__ void loadB4(s8v* dst, const short* p) {
    dst[0] = *(const s8v*)(p);
    dst[1] = *(const s8v*)(p + 32);
    dst[2] = *(const s8v*)(p + 64);
    dst[3] = *(const s8v*)(p + 96);
}
__device__ __forceinline__ void loadH5(s8v* dst, const short* p) {
    dst[0] = *(const s8v*)(p);
    dst[1] = *(const s8v*)(p + 32);
    dst[2] = *(const s8v*)(p + 64);
    dst[3] = *(const s8v*)(p + 96);
    dst[4] = *(const s8v*)(p + 128);
}

// ---------------------------------------------------------------------------
// prep: bf16 W^T regions + fp32 padded L1 weights / biases / transposed W3 + origin
// ---------------------------------------------------------------------------
__global__ void ngdv_prep(
    const float* __restrict__ tm1_w1, const float* __restrict__ tm1_b1,
    const float* __restrict__ tm1_w2, const float* __restrict__ tm1_b2,
    const float* __restrict__ tm1_w3, const float* __restrict__ tm1_b3,
    const float* __restrict__ tm2_w1, const float* __restrict__ tm2_b1,
    const float* __restrict__ tm2_w2, const float* __restrict__ tm2_b2,
    const float* __restrict__ tm2_w3, const float* __restrict__ tm2_b3,
    const float* __restrict__ vs_w1,  const float* __restrict__ vs_b1,
    const float* __restrict__ vs_w2,  const float* __restrict__ vs_b2,
    const float* __restrict__ vs_w3,
    const float* __restrict__ vv_w1,  const float* __restrict__ vv_b1,
    const float* __restrict__ vv_w2,  const float* __restrict__ vv_b2,
    const float* __restrict__ vv_w3,
    short* __restrict__ wsb, float* __restrict__ wsf, float* __restrict__ origin_out)
{
    const int tid = threadIdx.x;
    if (blockIdx.x < 564) {
        int idx = blockIdx.x * 256 + tid;
        if (idx < NSHORT) {
            short o;
            if (idx < WT_TM2)      { int n = idx >> 7, k = idx & 127; o = (n < H1 && k < H1) ? f2bf(tm1_w2[k*H1 + n]) : (short)0; }
            else if (idx < WT_VS)  { int r = idx - WT_TM2, n = r >> 7, k = r & 127; o = (n < H1 && k < H1) ? f2bf(tm2_w2[k*H1 + n]) : (short)0; }
            else if (idx < WT_VV)  { int r = idx - WT_VS,  n = r >> 7, k = r & 127; o = (n < H1 && k < H1) ? f2bf(vs_w2[k*H1 + n]) : (short)0; }
            else                   { int r = idx - WT_VV,  n = r / 320, k = r % 320; o = (n < H3 && k < H3) ? f2bf(vv_w2[k*H3 + n]) : (short)0; }
            wsb[idx] = o;
        } else {
            int f = idx - NSHORT;
            if (f < NFLOAT) {
                float v = 0.f;
                if (f < 256)       { int d = f >> 7, c = f & 127; if (c < H1) v = tm1_w1[d*H1 + c]; }
                else if (f < 384)  { int c = f - 256;  if (c < H1) v = tm1_b1[c]; }
                else if (f < 640)  { int r = f - 384, d = r >> 7, c = r & 127; if (c < H1) v = tm2_w1[d*H1 + c]; }
                else if (f < 768)  { int c = f - 640;  if (c < H1) v = tm2_b1[c]; }
                else if (f < 1024) { int r = f - 768, d = r >> 7, c = r & 127; if (c < H1) v = vs_w1[d*H1 + c]; }
                else if (f < 1152) { int c = f - 1024; if (c < H1) v = vs_b1[c]; }
                else if (f < 1792) { int r = f - 1152, d = r / 320, c = r % 320; if (c < H3) v = vv_w1[d*H3 + c]; }
                else if (f < 2112) { int c = f - 1792; if (c < H3) v = vv_b1[c]; }
                else if (f < 2240) { int c = f - 2112; if (c < H1) v = tm1_b2[c]; }
                else if (f < 2368) { int c = f - 2240; if (c < H1) v = tm2_b2[c]; }
                else if (f < 2496) { int c = f - 2368; if (c < H1) v = vs_b2[c]; }
                else if (f < 2816) { int c = f - 2496; if (c < H3) v = vv_b2[c]; }
                else if (f < 3072) { int r = f - 2816, i = r >> 7, c = r & 127; if (c < H1) v = tm1_w3[c*2 + i]; }
                else if (f < 3328) { int r = f - 3072, i = r >> 7, c = r & 127; if (c < H1) v = tm2_w3[c*2 + i]; }
                else if (f < 3456) { int c = f - 3328; if (c < H1) v = vs_w3[c]; }
                else               { int r = f - 3456, i = r / 320, c = r % 320; if (c < H3) v = vv_w3[c*2 + i]; }
                wsf[f] = v;
            }
        }
        return;
    }
    // origin block: taskmap(0). 256 threads: r = output idx, hf = k-half, shfl combine.
    __shared__ float h1[H1], h2[H1], y1o[2], g1[H1], g2[H1];
    const int r = tid >> 1, hf = tid & 1;
    const int k0 = hf ? 50 : 0, k1 = hf ? 100 : 50;
    if (tid < H1) h1[tid] = tanhf(tm1_b1[tid]);
    __syncthreads();
    {
        float acc = 0.f;
        if (r < H1) for (int k = k0; k < k1; ++k) acc += h1[k] * tm1_w2[k*H1 + r];
        acc += __shfl_xor(acc, 1, 64);
        if (r < H1 && !hf) h2[r] = tanhf(acc + tm1_b2[r]);
    }
    __syncthreads();
    if (tid < 2) {
        float acc = tm1_b3[tid];
        for (int k = 0; k < H1; ++k) acc += h2[k] * tm1_w3[k*2 + tid];
        y1o[tid] = acc;
    }
    __syncthreads();
    if (tid < H1) {
        float pre = tm2_b1[tid] + y1o[0]*tm2_w1[tid] + y1o[1]*tm2_w1[H1 + tid];
        g1[tid] = pre > 0.f ? pre : expm1f(pre);
    }
    __syncthreads();
    {
        float acc = 0.f;
        if (r < H1) for (int k = k0; k < k1; ++k) acc += g1[k] * tm2_w2[k*H1 + r];
        acc += __shfl_xor(acc, 1, 64);
        if (r < H1 && !hf) { float a = acc + tm2_b2[r]; g2[r] = a > 0.f ? a : expm1f(a); }
    }
    __syncthreads();
    if (tid < 2) {
        float acc = tm2_b3[tid];
        for (int k = 0; k < H1; ++k) acc += g2[k] * tm2_w3[k*2 + tid];
        float s = acc > 20.f ? acc : log1pf(expf(acc));
        origin_out[tid] = (1.f + s) * y1o[tid];
    }
}

// ---------------------------------------------------------------------------
// Main: ZERO LDS, register dataflow. R11: 32 points/wave (2 groups share every
// B-fragment + epilogue-constant load -> 2x compute per load) and
// launch_bounds(256,1) -> 256 VGPR cap so the scheduler can keep loads in
// flight (R9/R10's 128-cap serialized every VMEM at ~400cy).
// ---------------------------------------------------------------------------
__global__ __launch_bounds__(256, 1) void ngdv_main(
    const float* __restrict__ x,
    const float* __restrict__ tm1_b3, const float* __restrict__ tm2_b3,
    const float* __restrict__ vs_b3,  const float* __restrict__ vv_b3,
    const float* __restrict__ vv_a1,  const float* __restrict__ vv_a2,
    const short* __restrict__ wsb,    const float* __restrict__ wsf,
    const float* __restrict__ origin, float* __restrict__ out, int npts)
{
    const int tid = threadIdx.x;
    const int wv = tid >> 6, lane = tid & 63;
    const int fm = lane & 15, fq = lane >> 4;
    const int pbase = blockIdx.x*128 + wv*32 + fm;   // group g handles pbase + g*16
    float2 xv[2];
    #pragma unroll
    for (int g = 0; g < 2; ++g) {
        int p = pbase + g*16;
        xv[g] = (p < npts) ? *(const float2*)&x[p*2] : float2{0.f, 0.f};
    }
    const float a1v = vv_a1[0], a2v = vv_a2[0];
    const float og0 = origin[0], og1 = origin[1];

    s8v afp[2][4], aft0[2][4], aft1[2][4];
    s8v Ba[4], Bb[4];

    // ---- tm1 L1 (2->100) + tangent seeds, both groups
    #pragma unroll
    for (int ks = 0; ks < 4; ++ks) {
        int c0 = ks*32 + fq*8;
        #pragma unroll
        for (int hh = 0; hh < 2; ++hh) {
            f4v w0 = *(const f4v*)&wsf[F_TM1W1 + c0 + hh*4];
            f4v w1 = *(const f4v*)&wsf[F_TM1W1 + 128 + c0 + hh*4];
            f4v bv = *(const f4v*)&wsf[F_TM1B1 + c0 + hh*4];
            #pragma unroll
            for (int g = 0; g < 2; ++g) {
                #pragma unroll
                for (int e = 0; e < 4; ++e) {
                    int ee = hh*4 + e;
                    float pre = fmaf(xv[g].y, w1[e], fmaf(xv[g].x, w0[e], bv[e]));
                    float h = tanh_fast(pre), dd = 1.f - h*h;
                    afp[g][ks][ee] = f2bf(h);
                    aft0[g][ks][ee] = f2bf(w0[e]*dd);
                    aft1[g][ks][ee] = f2bf(w1[e]*dd);
                }
            }
        }
    }

    // ---- G1: [.x128]@tm1_w2, both groups per B-tile; epilogue folds tanh + L3
    float y1p[2][2] = {{0.f,0.f},{0.f,0.f}};
    float dyp[2][4] = {{0.f,0.f,0.f,0.f},{0.f,0.f,0.f,0.f}};
    {
        const short* bb = wsb + WT_TM1 + fm*128 + fq*8;
        loadB4(Ba, bb);
        #pragma unroll
        for (int nt = 0; nt < 7; ++nt) {
            s8v* cur = (nt & 1) ? Bb : Ba;
            s8v* nxt = (nt & 1) ? Ba : Bb;
            if (nt < 6) loadB4(nxt, bb + (nt+1)*2048);
            int col0 = nt*16 + fq*4;
            f4v bb2 = *(const f4v*)&wsf[F_TM1B2 + col0];
            f4v w0v = *(const f4v*)&wsf[F_TM1W3T + col0];
            f4v w1v = *(const f4v*)&wsf[F_TM1W3T + 128 + col0];
            #pragma unroll
            for (int g = 0; g < 2; ++g) {
                f4v cp = {0,0,0,0}, ct0 = {0,0,0,0}, ct1 = {0,0,0,0};
                cp  = mfma16(cur[0], afp[g][0], cp);   cp  = mfma16(cur[1], afp[g][1], cp);
                cp  = mfma16(cur[2], afp[g][2], cp);   cp  = mfma16(cur[3], afp[g][3], cp);
                ct0 = mfma16(cur[0], aft0[g][0], ct0); ct0 = mfma16(cur[1], aft0[g][1], ct0);
                ct0 = mfma16(cur[2], aft0[g][2], ct0); ct0 = mfma16(cur[3], aft0[g][3], ct0);
                ct1 = mfma16(cur[0], aft1[g][0], ct1); ct1 = mfma16(cur[1], aft1[g][1], ct1);
                ct1 = mfma16(cur[2], aft1[g][2], ct1); ct1 = mfma16(cur[3], aft1[g][3], ct1);
                #pragma unroll
                for (int r = 0; r < 4; ++r) {
                    float h = tanh_fast(cp[r] + bb2[r]);
                    float dd = 1.f - h*h;
                    float t0 = ct0[r]*dd, t1 = ct1[r]*dd;
                    y1p[g][0] = fmaf(h,  w0v[r], y1p[g][0]);
                    y1p[g][1] = fmaf(h,  w1v[r], y1p[g][1]);
                    dyp[g][0] = fmaf(t0, w0v[r], dyp[g][0]);
                    dyp[g][1] = fmaf(t0, w1v[r], dyp[g][1]);
                    dyp[g][2] = fmaf(t1, w0v[r], dyp[g][2]);
                    dyp[g][3] = fmaf(t1, w1v[r], dyp[g][3]);
                }
            }
        }
    }
    float y1[2][2], dy[2][4];
    #pragma unroll
    for (int g = 0; g < 2; ++g) {
        RED4(y1p[g][0]); RED4(y1p[g][1]);
        RED4(dyp[g][0]); RED4(dyp[g][1]); RED4(dyp[g][2]); RED4(dyp[g][3]);
        y1[g][0] = y1p[g][0] + tm1_b3[0] + xv[g].x;
        y1[g][1] = y1p[g][1] + tm1_b3[1] + xv[g].y;
        dy[g][0] = dyp[g][0] + 1.f; dy[g][1] = dyp[g][1];
        dy[g][2] = dyp[g][2];       dy[g][3] = dyp[g][3] + 1.f;
    }

    // ---- tm2 L1 (2->100) + tangent seeds
    #pragma unroll
    for (int ks = 0; ks < 4; ++ks) {
        int c0 = ks*32 + fq*8;
        #pragma unroll
        for (int hh = 0; hh < 2; ++hh) {
            f4v w0 = *(const f4v*)&wsf[F_TM2W1 + c0 + hh*4];
            f4v w1 = *(const f4v*)&wsf[F_TM2W1 + 128 + c0 + hh*4];
            f4v bv = *(const f4v*)&wsf[F_TM2B1 + c0 + hh*4];
            #pragma unroll
            for (int g = 0; g < 2; ++g) {
                #pragma unroll
                for (int e = 0; e < 4; ++e) {
                    int ee = hh*4 + e;
                    float pre = fmaf(y1[g][1], w1[e], fmaf(y1[g][0], w0[e], bv[e]));
                    float gg = pre > 0.f ? pre : (__expf(pre) - 1.f);
                    float dd = pre > 0.f ? 1.f : (gg + 1.f);
                    afp[g][ks][ee] = f2bf(gg);
                    aft0[g][ks][ee] = f2bf((dy[g][0]*w0[e] + dy[g][1]*w1[e]) * dd);
                    aft1[g][ks][ee] = f2bf((dy[g][2]*w0[e] + dy[g][3]*w1[e]) * dd);
                }
            }
        }
    }

    // ---- G2: @tm2_w2; epilogue folds elu + L3
    float spp[2][2] = {{0.f,0.f},{0.f,0.f}};
    float dsp[2][4] = {{0.f,0.f,0.f,0.f},{0.f,0.f,0.f,0.f}};
    {
        const short* bb = wsb + WT_TM2 + fm*128 + fq*8;
        loadB4(Ba, bb);
        #pragma unroll
        for (int nt = 0; nt < 7; ++nt) {
            s8v* cur = (nt & 1) ? Bb : Ba;
            s8v* nxt = (nt & 1) ? Ba : Bb;
            if (nt < 6) loadB4(nxt, bb + (nt+1)*2048);
            int col0 = nt*16 + fq*4;
            f4v bb2 = *(const f4v*)&wsf[F_TM2B2 + col0];
            f4v w0v = *(const f4v*)&wsf[F_TM2W3T + col0];
            f4v w1v = *(const f4v*)&wsf[F_TM2W3T + 128 + col0];
            #pragma unroll
            for (int g = 0; g < 2; ++g) {
                f4v cp = {0,0,0,0}, ct0 = {0,0,0,0}, ct1 = {0,0,0,0};
                cp  = mfma16(cur[0], afp[g][0], cp);   cp  = mfma16(cur[1], afp[g][1], cp);
                cp  = mfma16(cur[2], afp[g][2], cp);   cp  = mfma16(cur[3], afp[g][3], cp);
                ct0 = mfma16(cur[0], aft0[g][0], ct0); ct0 = mfma16(cur[1], aft0[g][1], ct0);
                ct0 = mfma16(cur[2], aft0[g][2], ct0); ct0 = mfma16(cur[3], aft0[g][3], ct0);
                ct1 = mfma16(cur[0], aft1[g][0], ct1); ct1 = mfma16(cur[1], aft1[g][1], ct1);
                ct1 = mfma16(cur[2], aft1[g][2], ct1); ct1 = mfma16(cur[3], aft1[g][3], ct1);
                #pragma unroll
                for (int r = 0; r < 4; ++r) {
                    float pre = cp[r] + bb2[r];
                    float gg = pre > 0.f ? pre : (__expf(pre) - 1.f);
                    float dd = pre > 0.f ? 1.f : (gg + 1.f);
                    float t0 = ct0[r]*dd, t1 = ct1[r]*dd;
                    spp[g][0] = fmaf(gg, w0v[r], spp[g][0]);
                    spp[g][1] = fmaf(gg, w1v[r], spp[g][1]);
                    dsp[g][0] = fmaf(t0, w0v[r], dsp[g][0]);
                    dsp[g][1] = fmaf(t0, w1v[r], dsp[g][1]);
                    dsp[g][2] = fmaf(t1, w0v[r], dsp[g][2]);
                    dsp[g][3] = fmaf(t1, w1v[r], dsp[g][3]);
                }
            }
        }
    }
    float ys[2][2], J[2][4];
    #pragma unroll
    for (int g = 0; g < 2; ++g) {
        RED4(spp[g][0]); RED4(spp[g][1]);
        RED4(dsp[g][0]); RED4(dsp[g][1]); RED4(dsp[g][2]); RED4(dsp[g][3]);
        float sp0 = spp[g][0] + tm2_b3[0], sp1 = spp[g][1] + tm2_b3[1];
        float s0 = sp0 > 20.f ? sp0 : __logf(1.f + __expf(sp0));
        float s1 = sp1 > 20.f ? sp1 : __logf(1.f + __expf(sp1));
        float sg0 = rcp_fast(1.f + __expf(-sp0));
        float sg1 = rcp_fast(1.f + __expf(-sp1));
        J[g][0] = dsp[g][0]*sg0*y1[g][0] + (1.f + s0)*dy[g][0];
        J[g][1] = dsp[g][2]*sg0*y1[g][0] + (1.f + s0)*dy[g][2];
        J[g][2] = dsp[g][1]*sg1*y1[g][1] + (1.f + s1)*dy[g][1];
        J[g][3] = dsp[g][3]*sg1*y1[g][1] + (1.f + s1)*dy[g][3];
        ys[g][0] = (1.f + s0)*y1[g][0] - og0;
        ys[g][1] = (1.f + s1)*y1[g][1] - og1;
    }

    // ---- vs L1 (2->100) (reuse afp)
    #pragma unroll
    for (int ks = 0; ks < 4; ++ks) {
        int c0 = ks*32 + fq*8;
        #pragma unroll
        for (int hh = 0; hh < 2; ++hh) {
            f4v w0 = *(const f4v*)&wsf[F_VSW1 + c0 + hh*4];
            f4v w1 = *(const f4v*)&wsf[F_VSW1 + 128 + c0 + hh*4];
            f4v bv = *(const f4v*)&wsf[F_VSB1 + c0 + hh*4];
            #pragma unroll
            for (int g = 0; g < 2; ++g)
                #pragma unroll
                for (int e = 0; e < 4; ++e)
                    afp[g][ks][hh*4+e] = f2bf(leakyf(fmaf(xv[g].y, w1[e], fmaf(xv[g].x, w0[e], bv[e]))));
        }
    }

    // ---- G3: @vs_w2; epilogue folds leaky + L3
    float lvp[2] = {0.f, 0.f};
    {
        const short* bb = wsb + WT_VS + fm*128 + fq*8;
        loadB4(Ba, bb);
        #pragma unroll
        for (int nt = 0; nt < 7; ++nt) {
            s8v* cur = (nt & 1) ? Bb : Ba;
            s8v* nxt = (nt & 1) ? Ba : Bb;
            if (nt < 6) loadB4(nxt, bb + (nt+1)*2048);
            int col0 = nt*16 + fq*4;
            f4v bb2 = *(const f4v*)&wsf[F_VSB2 + col0];
            f4v w0v = *(const f4v*)&wsf[F_VSW3T + col0];
            #pragma unroll
            for (int g = 0; g < 2; ++g) {
                f4v cp = {0,0,0,0};
                cp = mfma16(cur[0], afp[g][0], cp); cp = mfma16(cur[1], afp[g][1], cp);
                cp = mfma16(cur[2], afp[g][2], cp); cp = mfma16(cur[3], afp[g][3], cp);
                #pragma unroll
                for (int r = 0; r < 4; ++r)
                    lvp[g] = fmaf(leakyf(cp[r] + bb2[r]), w0v[r], lvp[g]);
            }
        }
    }
    float lv[2];
    #pragma unroll
    for (int g = 0; g < 2; ++g) { RED4(lvp[g]); lv[g] = lvp[g] + vs_b3[0]; }

    // ---- vv L1 (2->300) -> register A-frags, both groups
    s8v afw[2][10];
    #pragma unroll
    for (int ks = 0; ks < 10; ++ks) {
        int c0 = ks*32 + fq*8;
        #pragma unroll
        for (int hh = 0; hh < 2; ++hh) {
            f4v w0 = *(const f4v*)&wsf[F_VVW1 + c0 + hh*4];
            f4v w1 = *(const f4v*)&wsf[F_VVW1 + 320 + c0 + hh*4];
            f4v bv = *(const f4v*)&wsf[F_VVB1 + c0 + hh*4];
            #pragma unroll
            for (int g = 0; g < 2; ++g)
                #pragma unroll
                for (int e = 0; e < 4; ++e)
                    afw[g][ks][hh*4+e] = f2bf(preluf(fmaf(ys[g][1], w1[e], fmaf(ys[g][0], w0[e], bv[e])), a1v));
        }
    }

    // ---- G4: @vv_w2; 3-buffer half-tile pipeline; epilogue folds prelu + L3
    float dtp[2][2] = {{0.f,0.f},{0.f,0.f}};
    {
        const short* bb = wsb + WT_VV + fm*320 + fq*8;
        s8v H[3][5];
        loadH5(H[0], bb);            // tile0 half0
        loadH5(H[1], bb + 160);      // tile0 half1
        #pragma unroll
        for (int nt = 0; nt < 19; ++nt) {
            const int i0 = (2*nt) % 3, i1 = (2*nt + 1) % 3, i2 = (2*nt + 2) % 3;
            if (nt < 18) loadH5(H[i2], bb + (nt+1)*5120);          // next half0
            int col0 = nt*16 + fq*4;
            f4v bb2 = *(const f4v*)&wsf[F_VVB2 + col0];
            f4v w0v = *(const f4v*)&wsf[F_VVW3T + col0];
            f4v w1v = *(const f4v*)&wsf[F_VVW3T + 320 + col0];
            f4v c0a = {0,0,0,0}, c1a = {0,0,0,0};
            // half0 consumed by both groups
            c0a = mfma16(H[i0][0], afw[0][0], c0a); c0a = mfma16(H[i0][1], afw[0][1], c0a);
            c0a = mfma16(H[i0][2], afw[0][2], c0a); c0a = mfma16(H[i0][3], afw[0][3], c0a);
            c0a = mfma16(H[i0][4], afw[0][4], c0a);
            c1a = mfma16(H[i0][0], afw[1][0], c1a); c1a = mfma16(H[i0][1], afw[1][1], c1a);
            c1a = mfma16(H[i0][2], afw[1][2], c1a); c1a = mfma16(H[i0][3], afw[1][3], c1a);
            c1a = mfma16(H[i0][4], afw[1][4], c1a);
            if (nt < 18) loadH5(H[i0], bb + (nt+1)*5120 + 160);    // next half1 (reuses i0)
            c0a = mfma16(H[i1][0], afw[0][5], c0a); c0a = mfma16(H[i1][1], afw[0][6], c0a);
            c0a = mfma16(H[i1][2], afw[0][7], c0a); c0a = mfma16(H[i1][3], afw[0][8], c0a);
            c0a = mfma16(H[i1][4], afw[0][9], c0a);
            c1a = mfma16(H[i1][0], afw[1][5], c1a); c1a = mfma16(H[i1][1], afw[1][6], c1a);
            c1a = mfma16(H[i1][2], afw[1][7], c1a); c1a = mfma16(H[i1][3], afw[1][8], c1a);
            c1a = mfma16(H[i1][4], afw[1][9], c1a);
            #pragma unroll
            for (int r = 0; r < 4; ++r) {
                float v0 = preluf(c0a[r] + bb2[r], a2v);
                float v1 = preluf(c1a[r] + bb2[r], a2v);
                dtp[0][0] = fmaf(v0, w0v[r], dtp[0][0]);
                dtp[0][1] = fmaf(v0, w1v[r], dtp[0][1]);
                dtp[1][0] = fmaf(v1, w0v[r], dtp[1][0]);
                dtp[1][1] = fmaf(v1, w1v[r], dtp[1][1]);
            }
        }
    }

    // ---- combine & store, both groups
    #pragma unroll
    for (int g = 0; g < 2; ++g) {
        RED4(dtp[g][0]); RED4(dtp[g][1]);
        float dt0 = dtp[g][0] + vv_b3[0];
        float dt1 = dtp[g][1] + vv_b3[1];
        int p = pbase + g*16;
        if (fq == 0 && p < npts) {
            float y0 = ys[g][0], y1v = ys[g][1];
            float ls = dt0*y0 + dt1*y1v;
            float Vq = y0*y0 + y1v*y1v;
            float coef = fmaxf(ls + 1e-4f*Vq, 0.f) * rcp_fast(Vq + 1e-12f);
            float yd0 = dt0 - coef*y0, yd1 = dt1 - coef*y1v;
            float inv_n = rcp_fast(fmaxf(sqrtf(yd0*yd0 + yd1*yd1), 1e-12f));
            float yn0 = yd0*inv_n, yn1 = yd1*inv_n;
            float Ja = J[g][0], Jb = J[g][1], Jc = J[g][2], Jd = J[g][3];
            float invdet = rcp_fast(Ja*Jd - Jb*Jc);
            float xh0 = ( Jd*yn0 - Jb*yn1) * invdet;
            float xh1 = (-Jc*yn0 + Ja*yn1) * invdet;
            float2 o;
            o.x = (__expf(lv[g] + xv[g].x) + 1e-12f) * xh0;
            o.y = (__expf(lv[g] + xv[g].y) + 1e-12f) * xh1;
            *(float2*)&out[p*2] = o;
        }
    }
}

extern "C" void kernel_launch(void* const* d_in, const int* in_sizes, int n_in,
                              void* d_out, int out_size, void* d_ws, size_t ws_size,
                              hipStream_t stream) {
    const float* x      = (const float*)d_in[0];
    const float* tm1_w1 = (const float*)d_in[1];
    const float* tm1_b1 = (const float*)d_in[2];
    const float* tm1_w2 = (const float*)d_in[3];
    const float* tm1_b2 = (const float*)d_in[4];
    const float* tm1_w3 = (const float*)d_in[5];
    const float* tm1_b3 = (const float*)d_in[6];
    const float* tm2_w1 = (const float*)d_in[7];
    const float* tm2_b1 = (const float*)d_in[8];
    const float* tm2_w2 = (const float*)d_in[9];
    const float* tm2_b2 = (const float*)d_in[10];
    const float* tm2_w3 = (const float*)d_in[11];
    const float* tm2_b3 = (const float*)d_in[12];
    const float* vv_w1  = (const float*)d_in[13];
    const float* vv_b1  = (const float*)d_in[14];
    const float* vv_a1  = (const float*)d_in[15];
    const float* vv_w2  = (const float*)d_in[16];
    const float* vv_b2  = (const float*)d_in[17];
    const float* vv_a2  = (const float*)d_in[18];
    const float* vv_w3  = (const float*)d_in[19];
    const float* vv_b3  = (const float*)d_in[20];
    const float* vs_w1  = (const float*)d_in[21];
    const float* vs_b1  = (const float*)d_in[22];
    const float* vs_w2  = (const float*)d_in[23];
    const float* vs_b2  = (const float*)d_in[24];
    const float* vs_w3  = (const float*)d_in[25];
    const float* vs_b3  = (const float*)d_in[26];

    float* out       = (float*)d_out;
    float* origin_ws = (float*)d_ws;                            // 2 floats
    short* wsb       = (short*)((char*)d_ws + 64);              // bf16 regions
    float* wsf       = (float*)((char*)d_ws + 64 + NSHORT*2);   // fp32 padded region
    const int npts = in_sizes[0] / 2;
    const int nblk = (npts + 127) / 128;

    ngdv_prep<<<565, 256, 0, stream>>>(
        tm1_w1, tm1_b1, tm1_w2, tm1_b2, tm1_w3, tm1_b3,
        tm2_w1, tm2_b1, tm2_w2, tm2_b2, tm2_w3, tm2_b3,
        vs_w1, vs_b1, vs_w2, vs_b2, vs_w3,
        vv_w1, vv_b1, vv_w2, vv_b2, vv_w3,
        wsb, wsf, origin_ws);

    ngdv_main<<<nblk, 256, 0, stream>>>(
        x, tm1_b3, tm2_b3, vs_b3, vv_b3, vv_a1, vv_a2,
        wsb, wsf, origin_ws, out, npts);
}

// Round 12
// 245.622 us; speedup vs baseline: 1.7054x; 1.6524x over previous
//
#include <hip/hip_runtime.h>
#include <math.h>

#define H1 100
#define H3 300

// bf16 fragment-major B regions in d_ws (short-element offsets from byte 64)
// taskmap: [nt:7][ks:4][lane:64][e:8]  (value = W[k][n], n=nt*16+(lane&15),
//          k=ks*32+(lane>>4)*8+e, zero-padded)
// vv:      [nt:19][ks:10][lane:64][e:8]
#define WT_TM1    0
#define WT_TM2    14336
#define WT_VS     28672
#define WT_VV     43008
#define NSHORT    140288
// fp32 padded small-weight region (float-element offsets after bf16 region)
#define F_TM1W1   0
#define F_TM1B1   256
#define F_TM2W1   384
#define F_TM2B1   640
#define F_VSW1    768
#define F_VSB1    1024
#define F_VVW1    1152
#define F_VVB1    1792
#define F_TM1B2   2112
#define F_TM2B2   2240
#define F_VSB2    2368
#define F_VVB2    2496
#define F_TM1W3T  2816         // [2][128]
#define F_TM2W3T  3072         // [2][128]
#define F_VSW3T   3328         // [1][128]
#define F_VVW3T   3456         // [2][320]
#define NFLOAT    4096

typedef __attribute__((ext_vector_type(8))) short s8v;
typedef __attribute__((ext_vector_type(4))) float f4v;

__device__ __forceinline__ f4v mfma16(s8v a, s8v b, f4v c) {
    return __builtin_amdgcn_mfma_f32_16x16x32_bf16(a, b, c, 0, 0, 0);
}
__device__ __forceinline__ float rcp_fast(float v) { return __builtin_amdgcn_rcpf(v); }
__device__ __forceinline__ float tanh_fast(float v) {
    float t = __expf(2.f * v);
    return 1.f - 2.f * rcp_fast(t + 1.f);
}
__device__ __forceinline__ float leakyf(float v) { return v >= 0.f ? v : 0.01f * v; }
__device__ __forceinline__ float preluf(float v, float a) { return v >= 0.f ? v : a * v; }
__device__ __forceinline__ short f2bf(float f) {
    union { float f; unsigned u; } v; v.f = f;
    unsigned r = v.u + 0x7fffu + ((v.u >> 16) & 1u);   // RNE
    return (short)(r >> 16);
}
// reduce across the 4 fq lane-groups (lane bits 4,5); result in every lane
#define RED4(v) { v += __shfl_xor(v, 16, 64); v += __shfl_xor(v, 32, 64); }

// ---------------------------------------------------------------------------
// prep: fragment-major bf16 B regions + fp32 padded region + origin
// ---------------------------------------------------------------------------
__global__ void ngdv_prep(
    const float* __restrict__ tm1_w1, const float* __restrict__ tm1_b1,
    const float* __restrict__ tm1_w2, const float* __restrict__ tm1_b2,
    const float* __restrict__ tm1_w3, const float* __restrict__ tm1_b3,
    const float* __restrict__ tm2_w1, const float* __restrict__ tm2_b1,
    const float* __restrict__ tm2_w2, const float* __restrict__ tm2_b2,
    const float* __restrict__ tm2_w3, const float* __restrict__ tm2_b3,
    const float* __restrict__ vs_w1,  const float* __restrict__ vs_b1,
    const float* __restrict__ vs_w2,  const float* __restrict__ vs_b2,
    const float* __restrict__ vs_w3,
    const float* __restrict__ vv_w1,  const float* __restrict__ vv_b1,
    const float* __restrict__ vv_w2,  const float* __restrict__ vv_b2,
    const float* __restrict__ vv_w3,
    short* __restrict__ wsb, float* __restrict__ wsf, float* __restrict__ origin_out)
{
    const int tid = threadIdx.x;
    if (blockIdx.x < 564) {
        int idx = blockIdx.x * 256 + tid;
        if (idx < NSHORT) {
            short o;
            if (idx < WT_VV) {
                // taskmap fragment-major: region r in [0,14336)
                int rgn = idx / 14336, r = idx % 14336;
                const float* src = (rgn == 0) ? tm1_w2 : (rgn == 1) ? tm2_w2 : vs_w2;
                int nt = r >> 11, ks = (r >> 9) & 3, lane = (r >> 3) & 63, e = r & 7;
                int n = nt*16 + (lane & 15);
                int k = ks*32 + (lane >> 4)*8 + e;
                o = (n < H1 && k < H1) ? f2bf(src[k*H1 + n]) : (short)0;
            } else {
                int r = idx - WT_VV;
                int nt = r / 5120, rem = r % 5120;
                int ks = rem >> 9, lane = (rem >> 3) & 63, e = r & 7;
                int n = nt*16 + (lane & 15);
                int k = ks*32 + (lane >> 4)*8 + e;
                o = (n < H3 && k < H3) ? f2bf(vv_w2[k*H3 + n]) : (short)0;
            }
            wsb[idx] = o;
        } else {
            int f = idx - NSHORT;
            if (f < NFLOAT) {
                float v = 0.f;
                if (f < 256)       { int d = f >> 7, c = f & 127; if (c < H1) v = tm1_w1[d*H1 + c]; }
                else if (f < 384)  { int c = f - 256;  if (c < H1) v = tm1_b1[c]; }
                else if (f < 640)  { int r = f - 384, d = r >> 7, c = r & 127; if (c < H1) v = tm2_w1[d*H1 + c]; }
                else if (f < 768)  { int c = f - 640;  if (c < H1) v = tm2_b1[c]; }
                else if (f < 1024) { int r = f - 768, d = r >> 7, c = r & 127; if (c < H1) v = vs_w1[d*H1 + c]; }
                else if (f < 1152) { int c = f - 1024; if (c < H1) v = vs_b1[c]; }
                else if (f < 1792) { int r = f - 1152, d = r / 320, c = r % 320; if (c < H3) v = vv_w1[d*H3 + c]; }
                else if (f < 2112) { int c = f - 1792; if (c < H3) v = vv_b1[c]; }
                else if (f < 2240) { int c = f - 2112; if (c < H1) v = tm1_b2[c]; }
                else if (f < 2368) { int c = f - 2240; if (c < H1) v = tm2_b2[c]; }
                else if (f < 2496) { int c = f - 2368; if (c < H1) v = vs_b2[c]; }
                else if (f < 2816) { int c = f - 2496; if (c < H3) v = vv_b2[c]; }
                else if (f < 3072) { int r = f - 2816, i = r >> 7, c = r & 127; if (c < H1) v = tm1_w3[c*2 + i]; }
                else if (f < 3328) { int r = f - 3072, i = r >> 7, c = r & 127; if (c < H1) v = tm2_w3[c*2 + i]; }
                else if (f < 3456) { int c = f - 3328; if (c < H1) v = vs_w3[c]; }
                else               { int r = f - 3456, i = r / 320, c = r % 320; if (c < H3) v = vv_w3[c*2 + i]; }
                wsf[f] = v;
            }
        }
        return;
    }
    // origin block: taskmap(0)
    __shared__ float h1[H1], h2[H1], y1o[2], g1[H1], g2[H1];
    const int r = tid >> 1, hf = tid & 1;
    const int k0 = hf ? 50 : 0, k1 = hf ? 100 : 50;
    if (tid < H1) h1[tid] = tanhf(tm1_b1[tid]);
    __syncthreads();
    {
        float acc = 0.f;
        if (r < H1) for (int k = k0; k < k1; ++k) acc += h1[k] * tm1_w2[k*H1 + r];
        acc += __shfl_xor(acc, 1, 64);
        if (r < H1 && !hf) h2[r] = tanhf(acc + tm1_b2[r]);
    }
    __syncthreads();
    if (tid < 2) {
        float acc = tm1_b3[tid];
        for (int k = 0; k < H1; ++k) acc += h2[k] * tm1_w3[k*2 + tid];
        y1o[tid] = acc;
    }
    __syncthreads();
    if (tid < H1) {
        float pre = tm2_b1[tid] + y1o[0]*tm2_w1[tid] + y1o[1]*tm2_w1[H1 + tid];
        g1[tid] = pre > 0.f ? pre : expm1f(pre);
    }
    __syncthreads();
    {
        float acc = 0.f;
        if (r < H1) for (int k = k0; k < k1; ++k) acc += g1[k] * tm2_w2[k*H1 + r];
        acc += __shfl_xor(acc, 1, 64);
        if (r < H1 && !hf) { float a = acc + tm2_b2[r]; g2[r] = a > 0.f ? a : expm1f(a); }
    }
    __syncthreads();
    if (tid < 2) {
        float acc = tm2_b3[tid];
        for (int k = 0; k < H1; ++k) acc += g2[k] * tm2_w3[k*2 + tid];
        float s = acc > 20.f ? acc : log1pf(expf(acc));
        origin_out[tid] = (1.f + s) * y1o[tid];
    }
}

// ---------------------------------------------------------------------------
// Main: 512 threads = 8 waves x 16 pts. B staged ONCE PER BLOCK into LDS
// (fragment-major, conflict-free ds_read_b128); fp32 constants staged to LDS.
// Per-wave register dataflow + epilogue-folded L3 reductions as R9.
// LDS: 16K (LW) + 28K (TMB, reused G1/G2/G3) + 2x40K (VVB dbuf) = 127 KB.
// ---------------------------------------------------------------------------
__global__ __launch_bounds__(512, 2) void ngdv_main(
    const float* __restrict__ x,
    const float* __restrict__ tm1_b3, const float* __restrict__ tm2_b3,
    const float* __restrict__ vs_b3,  const float* __restrict__ vv_b3,
    const float* __restrict__ vv_a1,  const float* __restrict__ vv_a2,
    const short* __restrict__ wsb,    const float* __restrict__ wsf,
    const float* __restrict__ origin, float* __restrict__ out, int npts)
{
    __shared__ __align__(16) float LW[4096];
    __shared__ __align__(16) short TMB[14336];
    __shared__ __align__(16) short VVB[2][20480];

    const int tid = threadIdx.x;
    const int wv = tid >> 6, lane = tid & 63;
    const int fm = lane & 15, fq = lane >> 4;
    const int p = blockIdx.x*128 + wv*16 + fm;
    float2 xv = {0.f, 0.f};
    if (p < npts) xv = *(const float2*)&x[p*2];
    const float og0 = origin[0], og1 = origin[1];

    // ---- s0: stage LW (16KB) + TMB <- tm1_w2 frags
    for (int i = tid; i < 1024; i += 512) ((f4v*)LW)[i] = ((const f4v*)wsf)[i];
    {
        const s8v* s = (const s8v*)(wsb + WT_TM1);
        s8v* d = (s8v*)TMB;
        for (int i = tid; i < 1792; i += 512) d[i] = s[i];
    }
    __syncthreads();
    const float a1v = vv_a1[0], a2v = vv_a2[0];

    s8v afp[4], aft0[4], aft1[4];

    // ---- tm1 L1 (2->100) + tangent seeds (LW)
    #pragma unroll
    for (int ks = 0; ks < 4; ++ks) {
        int c0 = ks*32 + fq*8;
        #pragma unroll
        for (int hh = 0; hh < 2; ++hh) {
            f4v w0 = *(const f4v*)&LW[F_TM1W1 + c0 + hh*4];
            f4v w1 = *(const f4v*)&LW[F_TM1W1 + 128 + c0 + hh*4];
            f4v bv = *(const f4v*)&LW[F_TM1B1 + c0 + hh*4];
            #pragma unroll
            for (int e = 0; e < 4; ++e) {
                int ee = hh*4 + e;
                float pre = fmaf(xv.y, w1[e], fmaf(xv.x, w0[e], bv[e]));
                float h = tanh_fast(pre), dd = 1.f - h*h;
                afp[ks][ee] = f2bf(h);
                aft0[ks][ee] = f2bf(w0[e]*dd);
                aft1[ks][ee] = f2bf(w1[e]*dd);
            }
        }
    }

    // ---- G1: [48x128]@tm1_w2 (TMB); epilogue folds tanh + L3(tm1_w3)
    float y1p0 = 0.f, y1p1 = 0.f, dyp00 = 0.f, dyp01 = 0.f, dyp10 = 0.f, dyp11 = 0.f;
    #pragma unroll
    for (int nt = 0; nt < 7; ++nt) {
        s8v b0 = *(const s8v*)&TMB[(nt*4+0)*512 + lane*8];
        s8v b1 = *(const s8v*)&TMB[(nt*4+1)*512 + lane*8];
        s8v b2 = *(const s8v*)&TMB[(nt*4+2)*512 + lane*8];
        s8v b3 = *(const s8v*)&TMB[(nt*4+3)*512 + lane*8];
        f4v cp = {0,0,0,0}, ct0 = {0,0,0,0}, ct1 = {0,0,0,0};
        cp  = mfma16(b0, afp[0], cp);   cp  = mfma16(b1, afp[1], cp);
        cp  = mfma16(b2, afp[2], cp);   cp  = mfma16(b3, afp[3], cp);
        ct0 = mfma16(b0, aft0[0], ct0); ct0 = mfma16(b1, aft0[1], ct0);
        ct0 = mfma16(b2, aft0[2], ct0); ct0 = mfma16(b3, aft0[3], ct0);
        ct1 = mfma16(b0, aft1[0], ct1); ct1 = mfma16(b1, aft1[1], ct1);
        ct1 = mfma16(b2, aft1[2], ct1); ct1 = mfma16(b3, aft1[3], ct1);
        int col0 = nt*16 + fq*4;
        f4v bb2 = *(const f4v*)&LW[F_TM1B2 + col0];
        f4v w0v = *(const f4v*)&LW[F_TM1W3T + col0];
        f4v w1v = *(const f4v*)&LW[F_TM1W3T + 128 + col0];
        #pragma unroll
        for (int r = 0; r < 4; ++r) {
            float h = tanh_fast(cp[r] + bb2[r]);
            float dd = 1.f - h*h;
            float t0 = ct0[r]*dd, t1 = ct1[r]*dd;
            y1p0  = fmaf(h,  w0v[r], y1p0);  y1p1  = fmaf(h,  w1v[r], y1p1);
            dyp00 = fmaf(t0, w0v[r], dyp00); dyp01 = fmaf(t0, w1v[r], dyp01);
            dyp10 = fmaf(t1, w0v[r], dyp10); dyp11 = fmaf(t1, w1v[r], dyp11);
        }
    }
    RED4(y1p0); RED4(y1p1); RED4(dyp00); RED4(dyp01); RED4(dyp10); RED4(dyp11);
    const float y10 = y1p0 + tm1_b3[0] + xv.x;
    const float y11 = y1p1 + tm1_b3[1] + xv.y;
    const float dy00 = dyp00 + 1.f, dy01 = dyp01;
    const float dy10 = dyp10, dy11 = dyp11 + 1.f;
    __syncthreads();

    // ---- s2: TMB <- tm2_w2 frags
    {
        const s8v* s = (const s8v*)(wsb + WT_TM2);
        s8v* d = (s8v*)TMB;
        for (int i = tid; i < 1792; i += 512) d[i] = s[i];
    }
    __syncthreads();

    // ---- tm2 L1 (2->100) + tangent seeds
    #pragma unroll
    for (int ks = 0; ks < 4; ++ks) {
        int c0 = ks*32 + fq*8;
        #pragma unroll
        for (int hh = 0; hh < 2; ++hh) {
            f4v w0 = *(const f4v*)&LW[F_TM2W1 + c0 + hh*4];
            f4v w1 = *(const f4v*)&LW[F_TM2W1 + 128 + c0 + hh*4];
            f4v bv = *(const f4v*)&LW[F_TM2B1 + c0 + hh*4];
            #pragma unroll
            for (int e = 0; e < 4; ++e) {
                int ee = hh*4 + e;
                float pre = fmaf(y11, w1[e], fmaf(y10, w0[e], bv[e]));
                float g = pre > 0.f ? pre : (__expf(pre) - 1.f);
                float dd = pre > 0.f ? 1.f : (g + 1.f);
                afp[ks][ee] = f2bf(g);
                aft0[ks][ee] = f2bf((dy00*w0[e] + dy01*w1[e]) * dd);
                aft1[ks][ee] = f2bf((dy10*w0[e] + dy11*w1[e]) * dd);
            }
        }
    }

    // ---- G2: @tm2_w2 (TMB); epilogue folds elu + L3(tm2_w3)
    float spp0 = 0.f, spp1 = 0.f, dsp00 = 0.f, dsp01 = 0.f, dsp10 = 0.f, dsp11 = 0.f;
    #pragma unroll
    for (int nt = 0; nt < 7; ++nt) {
        s8v b0 = *(const s8v*)&TMB[(nt*4+0)*512 + lane*8];
        s8v b1 = *(const s8v*)&TMB[(nt*4+1)*512 + lane*8];
        s8v b2 = *(const s8v*)&TMB[(nt*4+2)*512 + lane*8];
        s8v b3 = *(const s8v*)&TMB[(nt*4+3)*512 + lane*8];
        f4v cp = {0,0,0,0}, ct0 = {0,0,0,0}, ct1 = {0,0,0,0};
        cp  = mfma16(b0, afp[0], cp);   cp  = mfma16(b1, afp[1], cp);
        cp  = mfma16(b2, afp[2], cp);   cp  = mfma16(b3, afp[3], cp);
        ct0 = mfma16(b0, aft0[0], ct0); ct0 = mfma16(b1, aft0[1], ct0);
        ct0 = mfma16(b2, aft0[2], ct0); ct0 = mfma16(b3, aft0[3], ct0);
        ct1 = mfma16(b0, aft1[0], ct1); ct1 = mfma16(b1, aft1[1], ct1);
        ct1 = mfma16(b2, aft1[2], ct1); ct1 = mfma16(b3, aft1[3], ct1);
        int col0 = nt*16 + fq*4;
        f4v bb2 = *(const f4v*)&LW[F_TM2B2 + col0];
        f4v w0v = *(const f4v*)&LW[F_TM2W3T + col0];
        f4v w1v = *(const f4v*)&LW[F_TM2W3T + 128 + col0];
        #pragma unroll
        for (int r = 0; r < 4; ++r) {
            float pre = cp[r] + bb2[r];
            float g = pre > 0.f ? pre : (__expf(pre) - 1.f);
            float dd = pre > 0.f ? 1.f : (g + 1.f);
            float t0 = ct0[r]*dd, t1 = ct1[r]*dd;
            spp0  = fmaf(g,  w0v[r], spp0);  spp1  = fmaf(g,  w1v[r], spp1);
            dsp00 = fmaf(t0, w0v[r], dsp00); dsp01 = fmaf(t0, w1v[r], dsp01);
            dsp10 = fmaf(t1, w0v[r], dsp10); dsp11 = fmaf(t1, w1v[r], dsp11);
        }
    }
    RED4(spp0); RED4(spp1); RED4(dsp00); RED4(dsp01); RED4(dsp10); RED4(dsp11);
    float ys0, ys1, Ja, Jb, Jc, Jd;
    {
        float sp0 = spp0 + tm2_b3[0], sp1 = spp1 + tm2_b3[1];
        float s0 = sp0 > 20.f ? sp0 : __logf(1.f + __expf(sp0));
        float s1 = sp1 > 20.f ? sp1 : __logf(1.f + __expf(sp1));
        float sg0 = rcp_fast(1.f + __expf(-sp0));
        float sg1 = rcp_fast(1.f + __expf(-sp1));
        Ja = dsp00*sg0*y10 + (1.f + s0)*dy00;
        Jb = dsp10*sg0*y10 + (1.f + s0)*dy10;
        Jc = dsp01*sg1*y11 + (1.f + s1)*dy01;
        Jd = dsp11*sg1*y11 + (1.f + s1)*dy11;
        ys0 = (1.f + s0)*y10 - og0;
        ys1 = (1.f + s1)*y11 - og1;
    }
    __syncthreads();

    // ---- s4: TMB <- vs_w2 frags
    {
        const s8v* s = (const s8v*)(wsb + WT_VS);
        s8v* d = (s8v*)TMB;
        for (int i = tid; i < 1792; i += 512) d[i] = s[i];
    }
    __syncthreads();

    // ---- vs L1 (2->100)
    #pragma unroll
    for (int ks = 0; ks < 4; ++ks) {
        int c0 = ks*32 + fq*8;
        #pragma unroll
        for (int hh = 0; hh < 2; ++hh) {
            f4v w0 = *(const f4v*)&LW[F_VSW1 + c0 + hh*4];
            f4v w1 = *(const f4v*)&LW[F_VSW1 + 128 + c0 + hh*4];
            f4v bv = *(const f4v*)&LW[F_VSB1 + c0 + hh*4];
            #pragma unroll
            for (int e = 0; e < 4; ++e)
                afp[ks][hh*4+e] = f2bf(leakyf(fmaf(xv.y, w1[e], fmaf(xv.x, w0[e], bv[e]))));
        }
    }

    // ---- G3: @vs_w2 (TMB); epilogue folds leaky + L3(vs_w3)
    float lvp = 0.f;
    #pragma unroll
    for (int nt = 0; nt < 7; ++nt) {
        s8v b0 = *(const s8v*)&TMB[(nt*4+0)*512 + lane*8];
        s8v b1 = *(const s8v*)&TMB[(nt*4+1)*512 + lane*8];
        s8v b2 = *(const s8v*)&TMB[(nt*4+2)*512 + lane*8];
        s8v b3 = *(const s8v*)&TMB[(nt*4+3)*512 + lane*8];
        f4v cp = {0,0,0,0};
        cp = mfma16(b0, afp[0], cp); cp = mfma16(b1, afp[1], cp);
        cp = mfma16(b2, afp[2], cp); cp = mfma16(b3, afp[3], cp);
        int col0 = nt*16 + fq*4;
        f4v bb2 = *(const f4v*)&LW[F_VSB2 + col0];
        f4v w0v = *(const f4v*)&LW[F_VSW3T + col0];
        #pragma unroll
        for (int r = 0; r < 4; ++r)
            lvp = fmaf(leakyf(cp[r] + bb2[r]), w0v[r], lvp);
    }
    RED4(lvp);
    const float lv = lvp + vs_b3[0];

    // ---- vv L1 (2->300) -> 10 register A-frags; stage VVB[0] (chunk 0)
    {
        const s8v* s = (const s8v*)(wsb + WT_VV);
        s8v* d = (s8v*)VVB[0];
        for (int i = tid; i < 2560; i += 512) d[i] = s[i];
    }
    s8v afw[10];
    #pragma unroll
    for (int ks = 0; ks < 10; ++ks) {
        int c0 = ks*32 + fq*8;
        #pragma unroll
        for (int hh = 0; hh < 2; ++hh) {
            f4v w0 = *(const f4v*)&LW[F_VVW1 + c0 + hh*4];
            f4v w1 = *(const f4v*)&LW[F_VVW1 + 320 + c0 + hh*4];
            f4v bv = *(const f4v*)&LW[F_VVB1 + c0 + hh*4];
            #pragma unroll
            for (int e = 0; e < 4; ++e)
                afw[ks][hh*4+e] = f2bf(preluf(fmaf(ys1, w1[e], fmaf(ys0, w0[e], bv[e])), a1v));
        }
    }
    __syncthreads();

    // ---- G4: @vv_w2 via 4-tile LDS chunks (double-buffered)
    float dtp0 = 0.f, dtp1 = 0.f;
    for (int c = 0; c < 5; ++c) {
        if (c < 4) {   // stage chunk c+1 into the other buffer
            int n16 = (c + 1 < 4) ? 2560 : 1920;
            const s8v* s = (const s8v*)(wsb + WT_VV + (c+1)*20480);
            s8v* d = (s8v*)VVB[(c+1) & 1];
            for (int i = tid; i < n16; i += 512) d[i] = s[i];
        }
        const short* VB = VVB[c & 1];
        int ntiles = (c < 4) ? 4 : 3;
        for (int t = 0; t < ntiles; ++t) {
            int nt = c*4 + t;
            f4v cp = {0,0,0,0};
            #pragma unroll
            for (int ks = 0; ks < 10; ++ks) {
                s8v bf = *(const s8v*)&VB[(t*10 + ks)*512 + lane*8];
                cp = mfma16(bf, afw[ks], cp);
            }
            int col0 = nt*16 + fq*4;
            f4v bb2 = *(const f4v*)&LW[F_VVB2 + col0];
            f4v w0v = *(const f4v*)&LW[F_VVW3T + col0];
            f4v w1v = *(const f4v*)&LW[F_VVW3T + 320 + col0];
            #pragma unroll
            for (int r = 0; r < 4; ++r) {
                float v = preluf(cp[r] + bb2[r], a2v);
                dtp0 = fmaf(v, w0v[r], dtp0);
                dtp1 = fmaf(v, w1v[r], dtp1);
            }
        }
        __syncthreads();
    }
    RED4(dtp0); RED4(dtp1);
    const float dt0 = dtp0 + vv_b3[0];
    const float dt1 = dtp1 + vv_b3[1];

    // ---- combine & store
    if (fq == 0 && p < npts) {
        float ls = dt0*ys0 + dt1*ys1;
        float Vq = ys0*ys0 + ys1*ys1;
        float coef = fmaxf(ls + 1e-4f*Vq, 0.f) * rcp_fast(Vq + 1e-12f);
        float yd0 = dt0 - coef*ys0, yd1 = dt1 - coef*ys1;
        float inv_n = rcp_fast(fmaxf(sqrtf(yd0*yd0 + yd1*yd1), 1e-12f));
        float yn0 = yd0*inv_n, yn1 = yd1*inv_n;
        float invdet = rcp_fast(Ja*Jd - Jb*Jc);
        float xh0 = ( Jd*yn0 - Jb*yn1) * invdet;
        float xh1 = (-Jc*yn0 + Ja*yn1) * invdet;
        float2 o;
        o.x = (__expf(lv + xv.x) + 1e-12f) * xh0;
        o.y = (__expf(lv + xv.y) + 1e-12f) * xh1;
        *(float2*)&out[p*2] = o;
    }
}

extern "C" void kernel_launch(void* const* d_in, const int* in_sizes, int n_in,
                              void* d_out, int out_size, void* d_ws, size_t ws_size,
                              hipStream_t stream) {
    const float* x      = (const float*)d_in[0];
    const float* tm1_w1 = (const float*)d_in[1];
    const float* tm1_b1 = (const float*)d_in[2];
    const float* tm1_w2 = (const float*)d_in[3];
    const float* tm1_b2 = (const float*)d_in[4];
    const float* tm1_w3 = (const float*)d_in[5];
    const float* tm1_b3 = (const float*)d_in[6];
    const float* tm2_w1 = (const float*)d_in[7];
    const float* tm2_b1 = (const float*)d_in[8];
    const float* tm2_w2 = (const float*)d_in[9];
    const float* tm2_b2 = (const float*)d_in[10];
    const float* tm2_w3 = (const float*)d_in[11];
    const float* tm2_b3 = (const float*)d_in[12];
    const float* vv_w1  = (const float*)d_in[13];
    const float* vv_b1  = (const float*)d_in[14];
    const float* vv_a1  = (const float*)d_in[15];
    const float* vv_w2  = (const float*)d_in[16];
    const float* vv_b2  = (const float*)d_in[17];
    const float* vv_a2  = (const float*)d_in[18];
    const float* vv_w3  = (const float*)d_in[19];
    const float* vv_b3  = (const float*)d_in[20];
    const float* vs_w1  = (const float*)d_in[21];
    const float* vs_b1  = (const float*)d_in[22];
    const float* vs_w2  = (const float*)d_in[23];
    const float* vs_b2  = (const float*)d_in[24];
    const float* vs_w3  = (const float*)d_in[25];
    const float* vs_b3  = (const float*)d_in[26];

    float* out       = (float*)d_out;
    float* origin_ws = (float*)d_ws;                            // 2 floats
    short* wsb       = (short*)((char*)d_ws + 64);              // bf16 regions
    float* wsf       = (float*)((char*)d_ws + 64 + NSHORT*2);   // fp32 padded region
    const int npts = in_sizes[0] / 2;
    const int nblk = (npts + 127) / 128;

    ngdv_prep<<<565, 256, 0, stream>>>(
        tm1_w1, tm1_b1, tm1_w2, tm1_b2, tm1_w3, tm1_b3,
        tm2_w1, tm2_b1, tm2_w2, tm2_b2, tm2_w3, tm2_b3,
        vs_w1, vs_b1, vs_w2, vs_b2, vs_w3,
        vv_w1, vv_b1, vv_w2, vv_b2, vv_w3,
        wsb, wsf, origin_ws);

    ngdv_main<<<nblk, 512, 0, stream>>>(
        x, tm1_b3, tm2_b3, vs_b3, vv_b3, vv_a1, vv_a2,
        wsb, wsf, origin_ws, out, npts);
}

// Round 13
// 234.732 us; speedup vs baseline: 1.7845x; 1.0464x over previous
//
#include <hip/hip_runtime.h>
#include <math.h>

#define H1 100
#define H3 300

// bf16 fragment-major B regions in d_ws (short-element offsets from byte 64)
// taskmap: [nt:7][ks:4][lane:64][e:8]  (value = W[k][n], n=nt*16+(lane&15),
//          k=ks*32+(lane>>4)*8+e, zero-padded)
// vv:      [nt:19][ks:10][lane:64][e:8]
#define WT_TM1    0
#define WT_TM2    14336
#define WT_VS     28672
#define WT_VV     43008
#define NSHORT    140288
// fp32 padded small-weight region (float-element offsets after bf16 region)
#define F_TM1W1   0
#define F_TM1B1   256
#define F_TM2W1   384
#define F_TM2B1   640
#define F_VSW1    768
#define F_VSB1    1024
#define F_VVW1    1152
#define F_VVB1    1792
#define F_TM1B2   2112
#define F_TM2B2   2240
#define F_VSB2    2368
#define F_VVB2    2496
#define F_TM1W3T  2816         // [2][128]
#define F_TM2W3T  3072         // [2][128]
#define F_VSW3T   3328         // [1][128]
#define F_VVW3T   3456         // [2][320]
#define NFLOAT    4096

typedef __attribute__((ext_vector_type(8))) short s8v;
typedef __attribute__((ext_vector_type(4))) float f4v;

__device__ __forceinline__ f4v mfma16(s8v a, s8v b, f4v c) {
    return __builtin_amdgcn_mfma_f32_16x16x32_bf16(a, b, c, 0, 0, 0);
}
__device__ __forceinline__ float rcp_fast(float v) { return __builtin_amdgcn_rcpf(v); }
__device__ __forceinline__ float tanh_fast(float v) {
    float t = __expf(2.f * v);
    return 1.f - 2.f * rcp_fast(t + 1.f);
}
__device__ __forceinline__ float leakyf(float v) { return v >= 0.f ? v : 0.01f * v; }
__device__ __forceinline__ float preluf(float v, float a) { return v >= 0.f ? v : a * v; }
__device__ __forceinline__ short f2bf(float f) {
    union { float f; unsigned u; } v; v.f = f;
    unsigned r = v.u + 0x7fffu + ((v.u >> 16) & 1u);   // RNE
    return (short)(r >> 16);
}
// reduce across the 4 fq lane-groups (lane bits 4,5); result in every lane
#define RED4(v) { v += __shfl_xor(v, 16, 64); v += __shfl_xor(v, 32, 64); }

// ---------------------------------------------------------------------------
// prep: fragment-major bf16 B regions + fp32 padded region + origin
// ---------------------------------------------------------------------------
__global__ void ngdv_prep(
    const float* __restrict__ tm1_w1, const float* __restrict__ tm1_b1,
    const float* __restrict__ tm1_w2, const float* __restrict__ tm1_b2,
    const float* __restrict__ tm1_w3, const float* __restrict__ tm1_b3,
    const float* __restrict__ tm2_w1, const float* __restrict__ tm2_b1,
    const float* __restrict__ tm2_w2, const float* __restrict__ tm2_b2,
    const float* __restrict__ tm2_w3, const float* __restrict__ tm2_b3,
    const float* __restrict__ vs_w1,  const float* __restrict__ vs_b1,
    const float* __restrict__ vs_w2,  const float* __restrict__ vs_b2,
    const float* __restrict__ vs_w3,
    const float* __restrict__ vv_w1,  const float* __restrict__ vv_b1,
    const float* __restrict__ vv_w2,  const float* __restrict__ vv_b2,
    const float* __restrict__ vv_w3,
    short* __restrict__ wsb, float* __restrict__ wsf, float* __restrict__ origin_out)
{
    const int tid = threadIdx.x;
    if (blockIdx.x < 564) {
        int idx = blockIdx.x * 256 + tid;
        if (idx < NSHORT) {
            short o;
            if (idx < WT_VV) {
                int rgn = idx / 14336, r = idx % 14336;
                const float* src = (rgn == 0) ? tm1_w2 : (rgn == 1) ? tm2_w2 : vs_w2;
                int nt = r >> 11, ks = (r >> 9) & 3, lane = (r >> 3) & 63, e = r & 7;
                int n = nt*16 + (lane & 15);
                int k = ks*32 + (lane >> 4)*8 + e;
                o = (n < H1 && k < H1) ? f2bf(src[k*H1 + n]) : (short)0;
            } else {
                int r = idx - WT_VV;
                int nt = r / 5120, rem = r % 5120;
                int ks = rem >> 9, lane = (rem >> 3) & 63, e = r & 7;
                int n = nt*16 + (lane & 15);
                int k = ks*32 + (lane >> 4)*8 + e;
                o = (n < H3 && k < H3) ? f2bf(vv_w2[k*H3 + n]) : (short)0;
            }
            wsb[idx] = o;
        } else {
            int f = idx - NSHORT;
            if (f < NFLOAT) {
                float v = 0.f;
                if (f < 256)       { int d = f >> 7, c = f & 127; if (c < H1) v = tm1_w1[d*H1 + c]; }
                else if (f < 384)  { int c = f - 256;  if (c < H1) v = tm1_b1[c]; }
                else if (f < 640)  { int r = f - 384, d = r >> 7, c = r & 127; if (c < H1) v = tm2_w1[d*H1 + c]; }
                else if (f < 768)  { int c = f - 640;  if (c < H1) v = tm2_b1[c]; }
                else if (f < 1024) { int r = f - 768, d = r >> 7, c = r & 127; if (c < H1) v = vs_w1[d*H1 + c]; }
                else if (f < 1152) { int c = f - 1024; if (c < H1) v = vs_b1[c]; }
                else if (f < 1792) { int r = f - 1152, d = r / 320, c = r % 320; if (c < H3) v = vv_w1[d*H3 + c]; }
                else if (f < 2112) { int c = f - 1792; if (c < H3) v = vv_b1[c]; }
                else if (f < 2240) { int c = f - 2112; if (c < H1) v = tm1_b2[c]; }
                else if (f < 2368) { int c = f - 2240; if (c < H1) v = tm2_b2[c]; }
                else if (f < 2496) { int c = f - 2368; if (c < H1) v = vs_b2[c]; }
                else if (f < 2816) { int c = f - 2496; if (c < H3) v = vv_b2[c]; }
                else if (f < 3072) { int r = f - 2816, i = r >> 7, c = r & 127; if (c < H1) v = tm1_w3[c*2 + i]; }
                else if (f < 3328) { int r = f - 3072, i = r >> 7, c = r & 127; if (c < H1) v = tm2_w3[c*2 + i]; }
                else if (f < 3456) { int c = f - 3328; if (c < H1) v = vs_w3[c]; }
                else               { int r = f - 3456, i = r / 320, c = r % 320; if (c < H3) v = vv_w3[c*2 + i]; }
                wsf[f] = v;
            }
        }
        return;
    }
    // origin block: taskmap(0). Parallelized: k-split GEMVs + shfl reductions.
    __shared__ float h1[H1], h2[H1], y1o[2], g1[H1], g2[H1];
    const int r = tid >> 1, hf = tid & 1;
    const int k0 = hf ? 50 : 0, k1 = hf ? 100 : 50;
    if (tid < H1) h1[tid] = tanhf(tm1_b1[tid]);
    __syncthreads();
    {
        float acc = 0.f;
        if (r < H1) for (int k = k0; k < k1; ++k) acc += h1[k] * tm1_w2[k*H1 + r];
        acc += __shfl_xor(acc, 1, 64);
        if (r < H1 && !hf) h2[r] = tanhf(acc + tm1_b2[r]);
    }
    __syncthreads();
    if (tid < 128) {   // y1o: 64 lanes per output i, shfl-tree
        int i = tid >> 6, ln = tid & 63;
        float acc = 0.f;
        if (ln < H1) acc += h2[ln] * tm1_w3[ln*2 + i];
        if (ln + 64 < H1) acc += h2[ln+64] * tm1_w3[(ln+64)*2 + i];
        #pragma unroll
        for (int off = 32; off >= 1; off >>= 1) acc += __shfl_xor(acc, off, 64);
        if (ln == 0) y1o[i] = acc + tm1_b3[i];
    }
    __syncthreads();
    if (tid < H1) {
        float pre = tm2_b1[tid] + y1o[0]*tm2_w1[tid] + y1o[1]*tm2_w1[H1 + tid];
        g1[tid] = pre > 0.f ? pre : expm1f(pre);
    }
    __syncthreads();
    {
        float acc = 0.f;
        if (r < H1) for (int k = k0; k < k1; ++k) acc += g1[k] * tm2_w2[k*H1 + r];
        acc += __shfl_xor(acc, 1, 64);
        if (r < H1 && !hf) { float a = acc + tm2_b2[r]; g2[r] = a > 0.f ? a : expm1f(a); }
    }
    __syncthreads();
    if (tid < 128) {
        int i = tid >> 6, ln = tid & 63;
        float acc = 0.f;
        if (ln < H1) acc += g2[ln] * tm2_w3[ln*2 + i];
        if (ln + 64 < H1) acc += g2[ln+64] * tm2_w3[(ln+64)*2 + i];
        #pragma unroll
        for (int off = 32; off >= 1; off >>= 1) acc += __shfl_xor(acc, off, 64);
        if (ln == 0) {
            float a = acc + tm2_b3[i];
            float s = a > 20.f ? a : log1pf(expf(a));
            origin_out[i] = (1.f + s) * y1o[i];
        }
    }
}

// ---------------------------------------------------------------------------
// Main: 512 threads = 8 waves x 16 pts. B staged once per block into LDS.
// R13: TMB/VVB merged into one 28 KB union buffer (VVB consumed as 1-tile
// 10 KB double-buffered chunks) -> LDS 127->44 KB; launch_bounds(512,4)
// -> 2 blocks/CU (16 waves/CU), 128-VGPR cap (use ~104, no spill).
// ---------------------------------------------------------------------------
__global__ __launch_bounds__(512, 4) void ngdv_main(
    const float* __restrict__ x,
    const float* __restrict__ tm1_b3, const float* __restrict__ tm2_b3,
    const float* __restrict__ vs_b3,  const float* __restrict__ vv_b3,
    const float* __restrict__ vv_a1,  const float* __restrict__ vv_a2,
    const short* __restrict__ wsb,    const float* __restrict__ wsf,
    const float* __restrict__ origin, float* __restrict__ out, int npts)
{
    __shared__ __align__(16) float LW[4096];     // 16 KB fp32 constants
    __shared__ __align__(16) short WB[14336];    // 28 KB union: taskmap B / vv dbuf

    const int tid = threadIdx.x;
    const int wv = tid >> 6, lane = tid & 63;
    const int fm = lane & 15, fq = lane >> 4;
    const int p = blockIdx.x*128 + wv*16 + fm;
    float2 xv = {0.f, 0.f};
    if (p < npts) xv = *(const float2*)&x[p*2];
    const float og0 = origin[0], og1 = origin[1];

    // ---- s0: stage LW (16KB) + WB <- tm1_w2 frags
    for (int i = tid; i < 1024; i += 512) ((f4v*)LW)[i] = ((const f4v*)wsf)[i];
    {
        const s8v* s = (const s8v*)(wsb + WT_TM1);
        s8v* d = (s8v*)WB;
        for (int i = tid; i < 1792; i += 512) d[i] = s[i];
    }
    __syncthreads();
    const float a1v = vv_a1[0], a2v = vv_a2[0];

    s8v afp[4], aft0[4], aft1[4];

    // ---- tm1 L1 (2->100) + tangent seeds (LW)
    #pragma unroll
    for (int ks = 0; ks < 4; ++ks) {
        int c0 = ks*32 + fq*8;
        #pragma unroll
        for (int hh = 0; hh < 2; ++hh) {
            f4v w0 = *(const f4v*)&LW[F_TM1W1 + c0 + hh*4];
            f4v w1 = *(const f4v*)&LW[F_TM1W1 + 128 + c0 + hh*4];
            f4v bv = *(const f4v*)&LW[F_TM1B1 + c0 + hh*4];
            #pragma unroll
            for (int e = 0; e < 4; ++e) {
                int ee = hh*4 + e;
                float pre = fmaf(xv.y, w1[e], fmaf(xv.x, w0[e], bv[e]));
                float h = tanh_fast(pre), dd = 1.f - h*h;
                afp[ks][ee] = f2bf(h);
                aft0[ks][ee] = f2bf(w0[e]*dd);
                aft1[ks][ee] = f2bf(w1[e]*dd);
            }
        }
    }

    // ---- G1: [48x128]@tm1_w2 (WB); epilogue folds tanh + L3(tm1_w3)
    float y1p0 = 0.f, y1p1 = 0.f, dyp00 = 0.f, dyp01 = 0.f, dyp10 = 0.f, dyp11 = 0.f;
    #pragma unroll
    for (int nt = 0; nt < 7; ++nt) {
        s8v b0 = *(const s8v*)&WB[(nt*4+0)*512 + lane*8];
        s8v b1 = *(const s8v*)&WB[(nt*4+1)*512 + lane*8];
        s8v b2 = *(const s8v*)&WB[(nt*4+2)*512 + lane*8];
        s8v b3 = *(const s8v*)&WB[(nt*4+3)*512 + lane*8];
        f4v cp = {0,0,0,0}, ct0 = {0,0,0,0}, ct1 = {0,0,0,0};
        cp  = mfma16(b0, afp[0], cp);   cp  = mfma16(b1, afp[1], cp);
        cp  = mfma16(b2, afp[2], cp);   cp  = mfma16(b3, afp[3], cp);
        ct0 = mfma16(b0, aft0[0], ct0); ct0 = mfma16(b1, aft0[1], ct0);
        ct0 = mfma16(b2, aft0[2], ct0); ct0 = mfma16(b3, aft0[3], ct0);
        ct1 = mfma16(b0, aft1[0], ct1); ct1 = mfma16(b1, aft1[1], ct1);
        ct1 = mfma16(b2, aft1[2], ct1); ct1 = mfma16(b3, aft1[3], ct1);
        int col0 = nt*16 + fq*4;
        f4v bb2 = *(const f4v*)&LW[F_TM1B2 + col0];
        f4v w0v = *(const f4v*)&LW[F_TM1W3T + col0];
        f4v w1v = *(const f4v*)&LW[F_TM1W3T + 128 + col0];
        #pragma unroll
        for (int r = 0; r < 4; ++r) {
            float h = tanh_fast(cp[r] + bb2[r]);
            float dd = 1.f - h*h;
            float t0 = ct0[r]*dd, t1 = ct1[r]*dd;
            y1p0  = fmaf(h,  w0v[r], y1p0);  y1p1  = fmaf(h,  w1v[r], y1p1);
            dyp00 = fmaf(t0, w0v[r], dyp00); dyp01 = fmaf(t0, w1v[r], dyp01);
            dyp10 = fmaf(t1, w0v[r], dyp10); dyp11 = fmaf(t1, w1v[r], dyp11);
        }
    }
    RED4(y1p0); RED4(y1p1); RED4(dyp00); RED4(dyp01); RED4(dyp10); RED4(dyp11);
    const float y10 = y1p0 + tm1_b3[0] + xv.x;
    const float y11 = y1p1 + tm1_b3[1] + xv.y;
    const float dy00 = dyp00 + 1.f, dy01 = dyp01;
    const float dy10 = dyp10, dy11 = dyp11 + 1.f;
    __syncthreads();

    // ---- s2: WB <- tm2_w2 frags
    {
        const s8v* s = (const s8v*)(wsb + WT_TM2);
        s8v* d = (s8v*)WB;
        for (int i = tid; i < 1792; i += 512) d[i] = s[i];
    }
    __syncthreads();

    // ---- tm2 L1 (2->100) + tangent seeds
    #pragma unroll
    for (int ks = 0; ks < 4; ++ks) {
        int c0 = ks*32 + fq*8;
        #pragma unroll
        for (int hh = 0; hh < 2; ++hh) {
            f4v w0 = *(const f4v*)&LW[F_TM2W1 + c0 + hh*4];
            f4v w1 = *(const f4v*)&LW[F_TM2W1 + 128 + c0 + hh*4];
            f4v bv = *(const f4v*)&LW[F_TM2B1 + c0 + hh*4];
            #pragma unroll
            for (int e = 0; e < 4; ++e) {
                int ee = hh*4 + e;
                float pre = fmaf(y11, w1[e], fmaf(y10, w0[e], bv[e]));
                float g = pre > 0.f ? pre : (__expf(pre) - 1.f);
                float dd = pre > 0.f ? 1.f : (g + 1.f);
                afp[ks][ee] = f2bf(g);
                aft0[ks][ee] = f2bf((dy00*w0[e] + dy01*w1[e]) * dd);
                aft1[ks][ee] = f2bf((dy10*w0[e] + dy11*w1[e]) * dd);
            }
        }
    }

    // ---- G2: @tm2_w2 (WB); epilogue folds elu + L3(tm2_w3)
    float spp0 = 0.f, spp1 = 0.f, dsp00 = 0.f, dsp01 = 0.f, dsp10 = 0.f, dsp11 = 0.f;
    #pragma unroll
    for (int nt = 0; nt < 7; ++nt) {
        s8v b0 = *(const s8v*)&WB[(nt*4+0)*512 + lane*8];
        s8v b1 = *(const s8v*)&WB[(nt*4+1)*512 + lane*8];
        s8v b2 = *(const s8v*)&WB[(nt*4+2)*512 + lane*8];
        s8v b3 = *(const s8v*)&WB[(nt*4+3)*512 + lane*8];
        f4v cp = {0,0,0,0}, ct0 = {0,0,0,0}, ct1 = {0,0,0,0};
        cp  = mfma16(b0, afp[0], cp);   cp  = mfma16(b1, afp[1], cp);
        cp  = mfma16(b2, afp[2], cp);   cp  = mfma16(b3, afp[3], cp);
        ct0 = mfma16(b0, aft0[0], ct0); ct0 = mfma16(b1, aft0[1], ct0);
        ct0 = mfma16(b2, aft0[2], ct0); ct0 = mfma16(b3, aft0[3], ct0);
        ct1 = mfma16(b0, aft1[0], ct1); ct1 = mfma16(b1, aft1[1], ct1);
        ct1 = mfma16(b2, aft1[2], ct1); ct1 = mfma16(b3, aft1[3], ct1);
        int col0 = nt*16 + fq*4;
        f4v bb2 = *(const f4v*)&LW[F_TM2B2 + col0];
        f4v w0v = *(const f4v*)&LW[F_TM2W3T + col0];
        f4v w1v = *(const f4v*)&LW[F_TM2W3T + 128 + col0];
        #pragma unroll
        for (int r = 0; r < 4; ++r) {
            float pre = cp[r] + bb2[r];
            float g = pre > 0.f ? pre : (__expf(pre) - 1.f);
            float dd = pre > 0.f ? 1.f : (g + 1.f);
            float t0 = ct0[r]*dd, t1 = ct1[r]*dd;
            spp0  = fmaf(g,  w0v[r], spp0);  spp1  = fmaf(g,  w1v[r], spp1);
            dsp00 = fmaf(t0, w0v[r], dsp00); dsp01 = fmaf(t0, w1v[r], dsp01);
            dsp10 = fmaf(t1, w0v[r], dsp10); dsp11 = fmaf(t1, w1v[r], dsp11);
        }
    }
    RED4(spp0); RED4(spp1); RED4(dsp00); RED4(dsp01); RED4(dsp10); RED4(dsp11);
    float ys0, ys1, Ja, Jb, Jc, Jd;
    {
        float sp0 = spp0 + tm2_b3[0], sp1 = spp1 + tm2_b3[1];
        float s0 = sp0 > 20.f ? sp0 : __logf(1.f + __expf(sp0));
        float s1 = sp1 > 20.f ? sp1 : __logf(1.f + __expf(sp1));
        float sg0 = rcp_fast(1.f + __expf(-sp0));
        float sg1 = rcp_fast(1.f + __expf(-sp1));
        Ja = dsp00*sg0*y10 + (1.f + s0)*dy00;
        Jb = dsp10*sg0*y10 + (1.f + s0)*dy10;
        Jc = dsp01*sg1*y11 + (1.f + s1)*dy01;
        Jd = dsp11*sg1*y11 + (1.f + s1)*dy11;
        ys0 = (1.f + s0)*y10 - og0;
        ys1 = (1.f + s1)*y11 - og1;
    }
    __syncthreads();

    // ---- s4: WB <- vs_w2 frags
    {
        const s8v* s = (const s8v*)(wsb + WT_VS);
        s8v* d = (s8v*)WB;
        for (int i = tid; i < 1792; i += 512) d[i] = s[i];
    }
    __syncthreads();

    // ---- vs L1 (2->100)
    #pragma unroll
    for (int ks = 0; ks < 4; ++ks) {
        int c0 = ks*32 + fq*8;
        #pragma unroll
        for (int hh = 0; hh < 2; ++hh) {
            f4v w0 = *(const f4v*)&LW[F_VSW1 + c0 + hh*4];
            f4v w1 = *(const f4v*)&LW[F_VSW1 + 128 + c0 + hh*4];
            f4v bv = *(const f4v*)&LW[F_VSB1 + c0 + hh*4];
            #pragma unroll
            for (int e = 0; e < 4; ++e)
                afp[ks][hh*4+e] = f2bf(leakyf(fmaf(xv.y, w1[e], fmaf(xv.x, w0[e], bv[e]))));
        }
    }

    // ---- G3: @vs_w2 (WB); epilogue folds leaky + L3(vs_w3)
    float lvp = 0.f;
    #pragma unroll
    for (int nt = 0; nt < 7; ++nt) {
        s8v b0 = *(const s8v*)&WB[(nt*4+0)*512 + lane*8];
        s8v b1 = *(const s8v*)&WB[(nt*4+1)*512 + lane*8];
        s8v b2 = *(const s8v*)&WB[(nt*4+2)*512 + lane*8];
        s8v b3 = *(const s8v*)&WB[(nt*4+3)*512 + lane*8];
        f4v cp = {0,0,0,0};
        cp = mfma16(b0, afp[0], cp); cp = mfma16(b1, afp[1], cp);
        cp = mfma16(b2, afp[2], cp); cp = mfma16(b3, afp[3], cp);
        int col0 = nt*16 + fq*4;
        f4v bb2 = *(const f4v*)&LW[F_VSB2 + col0];
        f4v w0v = *(const f4v*)&LW[F_VSW3T + col0];
        #pragma unroll
        for (int r = 0; r < 4; ++r)
            lvp = fmaf(leakyf(cp[r] + bb2[r]), w0v[r], lvp);
    }
    RED4(lvp);
    const float lv = lvp + vs_b3[0];
    __syncthreads();

    // ---- stage vv tile 0 into WB[0:5120]; vv L1 -> register A-frags
    {
        const s8v* s = (const s8v*)(wsb + WT_VV);
        s8v* d = (s8v*)WB;
        for (int i = tid; i < 640; i += 512) d[i] = s[i];
    }
    s8v afw[10];
    #pragma unroll
    for (int ks = 0; ks < 10; ++ks) {
        int c0 = ks*32 + fq*8;
        #pragma unroll
        for (int hh = 0; hh < 2; ++hh) {
            f4v w0 = *(const f4v*)&LW[F_VVW1 + c0 + hh*4];
            f4v w1 = *(const f4v*)&LW[F_VVW1 + 320 + c0 + hh*4];
            f4v bv = *(const f4v*)&LW[F_VVB1 + c0 + hh*4];
            #pragma unroll
            for (int e = 0; e < 4; ++e)
                afw[ks][hh*4+e] = f2bf(preluf(fmaf(ys1, w1[e], fmaf(ys0, w0[e], bv[e])), a1v));
        }
    }
    __syncthreads();

    // ---- G4: @vv_w2 via 1-tile LDS chunks (double-buffered inside WB)
    float dtp0 = 0.f, dtp1 = 0.f;
    for (int t = 0; t < 19; ++t) {
        if (t < 18) {   // stage tile t+1 into the other half
            const s8v* s = (const s8v*)(wsb + WT_VV + (t+1)*5120);
            s8v* d = (s8v*)(WB + ((t+1) & 1)*5120);
            for (int i = tid; i < 640; i += 512) d[i] = s[i];
        }
        const short* VB = WB + (t & 1)*5120;
        f4v cp = {0,0,0,0};
        #pragma unroll
        for (int ks = 0; ks < 10; ++ks) {
            s8v bf = *(const s8v*)&VB[ks*512 + lane*8];
            cp = mfma16(bf, afw[ks], cp);
        }
        int col0 = t*16 + fq*4;
        f4v bb2 = *(const f4v*)&LW[F_VVB2 + col0];
        f4v w0v = *(const f4v*)&LW[F_VVW3T + col0];
        f4v w1v = *(const f4v*)&LW[F_VVW3T + 320 + col0];
        #pragma unroll
        for (int r = 0; r < 4; ++r) {
            float v = preluf(cp[r] + bb2[r], a2v);
            dtp0 = fmaf(v, w0v[r], dtp0);
            dtp1 = fmaf(v, w1v[r], dtp1);
        }
        __syncthreads();
    }
    RED4(dtp0); RED4(dtp1);
    const float dt0 = dtp0 + vv_b3[0];
    const float dt1 = dtp1 + vv_b3[1];

    // ---- combine & store
    if (fq == 0 && p < npts) {
        float ls = dt0*ys0 + dt1*ys1;
        float Vq = ys0*ys0 + ys1*ys1;
        float coef = fmaxf(ls + 1e-4f*Vq, 0.f) * rcp_fast(Vq + 1e-12f);
        float yd0 = dt0 - coef*ys0, yd1 = dt1 - coef*ys1;
        float inv_n = rcp_fast(fmaxf(sqrtf(yd0*yd0 + yd1*yd1), 1e-12f));
        float yn0 = yd0*inv_n, yn1 = yd1*inv_n;
        float invdet = rcp_fast(Ja*Jd - Jb*Jc);
        float xh0 = ( Jd*yn0 - Jb*yn1) * invdet;
        float xh1 = (-Jc*yn0 + Ja*yn1) * invdet;
        float2 o;
        o.x = (__expf(lv + xv.x) + 1e-12f) * xh0;
        o.y = (__expf(lv + xv.y) + 1e-12f) * xh1;
        *(float2*)&out[p*2] = o;
    }
}

extern "C" void kernel_launch(void* const* d_in, const int* in_sizes, int n_in,
                              void* d_out, int out_size, void* d_ws, size_t ws_size,
                              hipStream_t stream) {
    const float* x      = (const float*)d_in[0];
    const float* tm1_w1 = (const float*)d_in[1];
    const float* tm1_b1 = (const float*)d_in[2];
    const float* tm1_w2 = (const float*)d_in[3];
    const float* tm1_b2 = (const float*)d_in[4];
    const float* tm1_w3 = (const float*)d_in[5];
    const float* tm1_b3 = (const float*)d_in[6];
    const float* tm2_w1 = (const float*)d_in[7];
    const float* tm2_b1 = (const float*)d_in[8];
    const float* tm2_w2 = (const float*)d_in[9];
    const float* tm2_b2 = (const float*)d_in[10];
    const float* tm2_w3 = (const float*)d_in[11];
    const float* tm2_b3 = (const float*)d_in[12];
    const float* vv_w1  = (const float*)d_in[13];
    const float* vv_b1  = (const float*)d_in[14];
    const float* vv_a1  = (const float*)d_in[15];
    const float* vv_w2  = (const float*)d_in[16];
    const float* vv_b2  = (const float*)d_in[17];
    const float* vv_a2  = (const float*)d_in[18];
    const float* vv_w3  = (const float*)d_in[19];
    const float* vv_b3  = (const float*)d_in[20];
    const float* vs_w1  = (const float*)d_in[21];
    const float* vs_b1  = (const float*)d_in[22];
    const float* vs_w2  = (const float*)d_in[23];
    const float* vs_b2  = (const float*)d_in[24];
    const float* vs_w3  = (const float*)d_in[25];
    const float* vs_b3  = (const float*)d_in[26];

    float* out       = (float*)d_out;
    float* origin_ws = (float*)d_ws;                            // 2 floats
    short* wsb       = (short*)((char*)d_ws + 64);              // bf16 regions
    float* wsf       = (float*)((char*)d_ws + 64 + NSHORT*2);   // fp32 padded region
    const int npts = in_sizes[0] / 2;
    const int nblk = (npts + 127) / 128;

    ngdv_prep<<<565, 256, 0, stream>>>(
        tm1_w1, tm1_b1, tm1_w2, tm1_b2, tm1_w3, tm1_b3,
        tm2_w1, tm2_b1, tm2_w2, tm2_b2, tm2_w3, tm2_b3,
        vs_w1, vs_b1, vs_w2, vs_b2, vs_w3,
        vv_w1, vv_b1, vv_w2, vv_b2, vv_w3,
        wsb, wsf, origin_ws);

    ngdv_main<<<nblk, 512, 0, stream>>>(
        x, tm1_b3, tm2_b3, vs_b3, vv_b3, vv_a1, vv_a2,
        wsb, wsf, origin_ws, out, npts);
}